// Round 1
// baseline (7657.711 us; speedup 1.0000x reference)
//
#include <hip/hip_runtime.h>
#include <hip/hip_fp16.h>
#include <math.h>

#define TID ((int)threadIdx.x)

// dims
// V=30000 K=50 E=300 T=60 B=128 TH=800 H=200 L=3
static __device__ __forceinline__ float sigf(float x){ return 1.f/(1.f+expf(-x)); }

// ---------------- init ----------------
__global__ void k_zero(float* acc){ if (TID<8) acc[TID]=0.f; }

// ---------------- alphas + kl_alpha ----------------
__global__ void k_alphas(const float* __restrict__ mqa, const float* __restrict__ lqa,
                         const float* __restrict__ eps, float* __restrict__ alphas){
  int i = blockIdx.x*256+TID; if (i>=900000) return;
  int t = i/15000, r = i%15000, k = r/300, e = r%300;
  int src = k*18000 + t*300 + e;
  float mu = mqa[src], ls = lqa[src];
  alphas[i] = mu + eps[i]*expf(0.5f*ls);
}

__global__ void k_klalpha(const float* __restrict__ mqa, const float* __restrict__ lqa,
                          const float* __restrict__ alphas, float* acc){
  __shared__ float red[256];
  int i = blockIdx.x*256+TID;
  float term = 0.f;
  if (i<900000){
    int t = i/15000, r = i%15000, k = r/300, e = r%300;
    int src = k*18000 + t*300 + e;
    float mu = mqa[src], ls = lqa[src];
    if (t==0){
      term = (expf(ls)+mu*mu)*(1.0f/(1.0f+1e-6f)) - 1.f - ls;
    } else {
      float d = mu - alphas[i-15000];
      term = (expf(ls)+d*d)*(1.0f/(0.005f+1e-6f)) - 1.f + logf(0.005f) - ls;
    }
  }
  red[TID]=term; __syncthreads();
  for (int s=128;s>0;s>>=1){ if (TID<s) red[TID]+=red[TID+s]; __syncthreads(); }
  if (TID==0) atomicAdd(acc+0, 0.5f*red[0]);
}

// ---------------- inp_map = rnn_inp @ Wmap.T + bmap ----------------
__global__ void k_iminit(float* __restrict__ im, const float* __restrict__ bmap){
  int i = blockIdx.x*256+TID; if (i<12000) im[i] = bmap[i%200];
}

__global__ void k_imgemm(const float* __restrict__ rnn, const float* __restrict__ Wmap,
                         float* __restrict__ im){
  int i = blockIdx.x*256+TID; if (i>=12000) return;
  int t = i%60, h = i/60;
  int k0 = blockIdx.y*3750;
  const float* rp = rnn + t*30000 + k0;
  const float* wp = Wmap + h*30000 + k0;
  float a = 0.f;
  #pragma unroll 4
  for (int c=0;c<3750;c++) a = fmaf(rp[c], wp[c], a);
  atomicAdd(&im[t*200+h], a);
}

// ---------------- LSTM pre-gates: pre[t][r] = Wih@x_t + bih + bhh ----------------
__global__ void k_pregates(const float* __restrict__ x, const float* __restrict__ Wih,
                           const float* __restrict__ bih, const float* __restrict__ bhh,
                           float* __restrict__ pre){
  __shared__ float xS[200];
  int t = blockIdx.x;
  if (TID<200) xS[TID] = x[t*200+TID];
  __syncthreads();
  int r = blockIdx.y*256 + TID;
  if (r>=800) return;
  float a = bih[r] + bhh[r];
  const float* wp = Wih + r*200;
  #pragma unroll 4
  for (int c=0;c<200;c++) a = fmaf(wp[c], xS[c], a);
  pre[t*800+r] = a;
}

// ---------------- LSTM recurrent (single block; Whh in regs as f16) ----------------
__global__ __launch_bounds__(768,3) void k_lstm(const float* __restrict__ pre,
        const float* __restrict__ Whh, float* __restrict__ out){
  __shared__ __align__(16) float hs[200];
  __shared__ float cs[200];
  __shared__ float gsh[800];
  __shared__ float wext[32*201];
  for (int i=TID;i<6400;i+=768){ int r=i/200,c=i%200; wext[r*201+c]=Whh[(768+r)*200+c]; }
  __half2 w[100];
  {
    const float4* wr = reinterpret_cast<const float4*>(Whh + TID*200);
    #pragma unroll
    for (int i=0;i<50;i++){
      float4 v = wr[i];
      w[2*i]   = __halves2half2(__float2half_rn(v.x), __float2half_rn(v.y));
      w[2*i+1] = __halves2half2(__float2half_rn(v.z), __float2half_rn(v.w));
    }
  }
  if (TID<200){ hs[TID]=0.f; cs[TID]=0.f; }
  __syncthreads();
  for (int t=0;t<60;t++){
    float a = pre[t*800+TID];
    const float4* h4 = reinterpret_cast<const float4*>(hs);
    #pragma unroll
    for (int i=0;i<50;i++){
      float4 hv = h4[i];
      float2 p = __half22float2(w[2*i]);
      float2 q = __half22float2(w[2*i+1]);
      a = fmaf(p.x,hv.x,a); a = fmaf(p.y,hv.y,a);
      a = fmaf(q.x,hv.z,a); a = fmaf(q.y,hv.w,a);
    }
    gsh[TID] = a;
    if (TID<32){
      float a2 = pre[t*800+768+TID];
      const float* we = &wext[TID*201];
      #pragma unroll 4
      for (int c=0;c<200;c++) a2 = fmaf(we[c], hs[c], a2);
      gsh[768+TID] = a2;
    }
    __syncthreads();
    if (TID<200){
      float ii=gsh[TID], ff=gsh[200+TID], gg=gsh[400+TID], oo=gsh[600+TID];
      float c = sigf(ff)*cs[TID] + sigf(ii)*tanhf(gg);
      cs[TID]=c;
      float h = sigf(oo)*tanhf(c);
      hs[TID]=h;
      out[t*200+TID]=h;
    }
    __syncthreads();
  }
}

// ---------------- eta chain (single block) ----------------
__global__ void k_eta(const float* __restrict__ outF, const float* __restrict__ Wmu,
                      const float* __restrict__ bmu, const float* __restrict__ Wls,
                      const float* __restrict__ bls, const float* __restrict__ eps,
                      float* __restrict__ etas, float* acc){
  __shared__ __half wS[100*254];  // rows 0..49 Wmu, 50..99 Wls, padded stride 254
  __shared__ float inp[256];      // [0,200)=lstm out, [200,250)=eta_prev
  __shared__ float pt[200];
  __shared__ float muS[64], lsS[64];
  for (int i=TID;i<12500;i+=256) wS[(i/250)*254 + (i%250)] = __float2half_rn(Wmu[i]);
  for (int i=TID;i<12500;i+=256) wS[(50+i/250)*254 + (i%250)] = __float2half_rn(Wls[i]);
  if (TID<50) inp[200+TID]=0.f;
  const float LOGD = logf(0.005f);
  float kacc = 0.f;
  __syncthreads();
  for (int t=0;t<60;t++){
    if (TID<200) inp[TID] = outF[t*200+TID];
    __syncthreads();
    if (TID<200){
      int rr = TID%100, hf = TID/100;
      const __half* wp = &wS[rr*254 + hf*125];
      const float* ip = &inp[hf*125];
      float s=0.f;
      for (int c=0;c<125;c++) s = fmaf(__half2float(wp[c]), ip[c], s);
      pt[TID]=s;
    }
    __syncthreads();
    if (TID<100){
      float v = pt[TID]+pt[TID+100];
      if (TID<50) muS[TID] = v + bmu[TID];
      else lsS[TID-50] = v + bls[TID-50];
    }
    __syncthreads();
    if (TID<64){
      float term=0.f;
      if (TID<50){
        float mu=muS[TID], ls=lsS[TID], ep=inp[200+TID];
        if (t==0) term = (expf(ls)+mu*mu)*(1.0f/(1.0f+1e-6f)) - 1.f - ls;
        else { float d=mu-ep; term = (expf(ls)+d*d)*(1.0f/(0.005f+1e-6f)) - 1.f + LOGD - ls; }
        float et = mu + eps[t*50+TID]*expf(0.5f*ls);
        etas[t*50+TID]=et;
        inp[200+TID]=et;
      }
      for (int o=32;o>0;o>>=1) term += __shfl_down(term,o);
      if (TID==0) kacc += 0.5f*term;
    }
    __syncthreads();
  }
  if (TID==0) atomicAdd(acc+1, kacc);
}

// ---------------- h1 = qt_in @ W1.T + b1 (atomic k-split GEMM) ----------------
__global__ void k_h1init(float* __restrict__ h1, const float* __restrict__ b1){
  int i = blockIdx.x*256+TID; if (i<102400) h1[i] = b1[i%800];
}

__global__ void k_h1gemm(const float* __restrict__ nb, const int* __restrict__ times,
                         const float* __restrict__ etas, const float* __restrict__ W1,
                         float* __restrict__ h1){
  __shared__ __align__(16) float As[16*132];
  __shared__ __align__(16) float Ws[16*68];
  __shared__ int tS[128];
  if (TID<128) tS[TID]=times[TID];
  int rt = blockIdx.x, sp = blockIdx.y;
  int kbeg = sp*940;
  int kend = (kbeg+940<30050)?(kbeg+940):30050;
  int b0 = (TID%32)*4, r0 = (TID/32)*8;
  float acc[32];
  #pragma unroll
  for (int j=0;j<32;j++) acc[j]=0.f;
  for (int kb=kbeg; kb<kend; kb+=16){
    __syncthreads();
    for (int i=TID;i<2048;i+=256){
      int b=i/16, kk=i%16, kg=kb+kk;
      float v=0.f;
      if (kg<kend){ v = (kg<30000)? nb[b*30000+kg] : etas[tS[b]*50 + (kg-30000)]; }
      As[kk*132+b]=v;
    }
    for (int i=TID;i<1024;i+=256){
      int r=i/16, kk=i%16, kg=kb+kk, rg=rt*64+r;
      float v=0.f;
      if (kg<kend && rg<800) v = W1[rg*30050+kg];
      Ws[kk*68+r]=v;
    }
    __syncthreads();
    #pragma unroll
    for (int kk=0;kk<16;kk++){
      float4 a4 = *reinterpret_cast<const float4*>(&As[kk*132+b0]);
      float4 w4 = *reinterpret_cast<const float4*>(&Ws[kk*68+r0]);
      float4 w5 = *reinterpret_cast<const float4*>(&Ws[kk*68+r0+4]);
      float aa[4]={a4.x,a4.y,a4.z,a4.w};
      float ww[8]={w4.x,w4.y,w4.z,w4.w,w5.x,w5.y,w5.z,w5.w};
      #pragma unroll
      for (int j=0;j<4;j++)
        #pragma unroll
        for (int i2=0;i2<8;i2++) acc[j*8+i2] = fmaf(aa[j], ww[i2], acc[j*8+i2]);
    }
  }
  #pragma unroll
  for (int j=0;j<4;j++){
    int b=b0+j;
    #pragma unroll
    for (int i2=0;i2<8;i2++){
      int rg = rt*64+r0+i2;
      if (rg<800) atomicAdd(&h1[b*800+rg], acc[j*8+i2]);
    }
  }
}

// ---------------- h2 = relu(relu(h1) @ W2.T + b2) ----------------
__global__ void k_h2(const float* __restrict__ h1, const float* __restrict__ W2,
                     const float* __restrict__ b2, float* __restrict__ h2){
  __shared__ float h1S[800];
  int b = blockIdx.x;
  for (int i=TID;i<800;i+=256) h1S[i] = fmaxf(h1[b*800+i], 0.f);
  __syncthreads();
  int r = blockIdx.y*256 + TID;
  if (r>=800) return;
  float a = b2[r];
  const float* wp = W2 + r*800;
  #pragma unroll 4
  for (int c=0;c<800;c++) a = fmaf(wp[c], h1S[c], a);
  h2[b*800+r] = fmaxf(a, 0.f);
}

// ---------------- mu_th / ls_th ----------------
__global__ void k_muls(const float* __restrict__ h2, const float* __restrict__ Wmu,
                       const float* __restrict__ bmu, const float* __restrict__ Wls,
                       const float* __restrict__ bls, float* __restrict__ muth,
                       float* __restrict__ lsth){
  __shared__ float hS[800];
  int b = blockIdx.x;
  for (int i=TID;i<800;i+=128) hS[i] = h2[b*800+i];
  __syncthreads();
  if (TID<50){
    float a = bmu[TID];
    const float* wp = Wmu + TID*800;
    #pragma unroll 4
    for (int c=0;c<800;c++) a = fmaf(wp[c], hS[c], a);
    muth[b*50+TID]=a;
  } else if (TID>=64 && TID<114){
    int r = TID-64;
    float a = bls[r];
    const float* wp = Wls + r*800;
    #pragma unroll 4
    for (int c=0;c<800;c++) a = fmaf(wp[c], hS[c], a);
    lsth[b*50+r]=a;
  }
}

// ---------------- theta + kl_theta ----------------
__global__ void k_theta(const float* __restrict__ muth, const float* __restrict__ lsth,
                        const float* __restrict__ etas, const int* __restrict__ times,
                        const float* __restrict__ epsth, float* __restrict__ theta,
                        float* acc){
  int b = blockIdx.x, k = TID;
  bool a = k<50;
  int tb = times[b];
  float mu=0.f, ls=0.f, etd=0.f, z=-INFINITY;
  if (a){
    mu = muth[b*50+k]; ls = lsth[b*50+k]; etd = etas[tb*50+k];
    z = mu + epsth[b*50+k]*expf(0.5f*ls);
  }
  float m=z;
  for (int o=32;o>0;o>>=1) m = fmaxf(m, __shfl_xor(m,o));
  float e = a ? expf(z-m) : 0.f;
  float s = e;
  for (int o=32;o>0;o>>=1) s += __shfl_xor(s,o);
  if (a) theta[b*50+k] = e/s;
  float term = a ? ((expf(ls)+(mu-etd)*(mu-etd))*(1.0f/(1.0f+1e-6f)) - 1.f - ls) : 0.f;
  for (int o=32;o>0;o>>=1) term += __shfl_xor(term,o);
  if (TID==0) atomicAdd(acc+2, 0.5f*term);
}

// ---------------- beta pass 1: per-(t,k) max / sumexp partials ----------------
__global__ __launch_bounds__(256) void k_pass1(const float* __restrict__ alphas,
        const float* __restrict__ rho, float* __restrict__ Mp, float* __restrict__ Sp){
  int t = blockIdx.y, vb = blockIdx.x, v0 = vb*120;
  __shared__ float aS[50*50];    // [e][k]
  __shared__ float rS[50*120];   // [e][v]
  __shared__ float tS[50*120];   // [k][v]
  float acc[25];
  #pragma unroll
  for (int j=0;j<25;j++) acc[j]=0.f;
  int ki=TID/24, vi=TID%24; bool act = TID<240;
  const float* aG = alphas + t*15000;
  for (int et=0; et<6; et++){
    for (int i=TID;i<2500;i+=256){ int k=i/50, e=i%50; aS[e*50+k]=aG[k*300+et*50+e]; }
    for (int i=TID;i<6000;i+=256){ int v=i/50, e=i%50; rS[e*120+v]=rho[(v0+v)*300+et*50+e]; }
    __syncthreads();
    if (act){
      for (int e=0;e<50;e++){
        const float* ap=&aS[e*50+ki*5];
        const float* rp=&rS[e*120+vi*5];
        float av[5], bv[5];
        #pragma unroll
        for (int j=0;j<5;j++){ av[j]=ap[j]; bv[j]=rp[j]; }
        #pragma unroll
        for (int j=0;j<5;j++)
          #pragma unroll
          for (int i2=0;i2<5;i2++) acc[j*5+i2] = fmaf(av[j],bv[i2],acc[j*5+i2]);
      }
    }
    __syncthreads();
  }
  if (act){
    #pragma unroll
    for (int j=0;j<5;j++)
      #pragma unroll
      for (int i2=0;i2<5;i2++) tS[(ki*5+j)*120 + vi*5+i2] = acc[j*5+i2];
  }
  __syncthreads();
  if (TID<50){
    const float* row=&tS[TID*120];
    float m=-INFINITY;
    for (int v=0;v<120;v++) m=fmaxf(m,row[v]);
    float s=0.f;
    for (int v=0;v<120;v++) s+=expf(row[v]-m);
    Mp[(t*50+TID)*250+vb]=m;
    Sp[(t*50+TID)*250+vb]=s;
  }
}

// ---------------- reduce partials -> M, 1/S ----------------
__global__ void k_msred(const float* __restrict__ Mp, const float* __restrict__ Sp,
                        float* __restrict__ Mg, float* __restrict__ iSg){
  __shared__ float red[256];
  int row = blockIdx.x;
  float m = (TID<250) ? Mp[row*250+TID] : -INFINITY;
  red[TID]=m; __syncthreads();
  for (int s=128;s>0;s>>=1){ if (TID<s) red[TID]=fmaxf(red[TID],red[TID+s]); __syncthreads(); }
  float M = red[0]; __syncthreads();
  float sv = (TID<250) ? Sp[row*250+TID]*expf(m-M) : 0.f;
  red[TID]=sv; __syncthreads();
  for (int s=128;s>0;s>>=1){ if (TID<s) red[TID]+=red[TID+s]; __syncthreads(); }
  if (TID==0){ Mg[row]=M; iSg[row]=1.f/red[0]; }
}

// ---------------- beta pass 2: recompute logits, fuse nll ----------------
__global__ __launch_bounds__(256) void k_pass2(const float* __restrict__ alphas,
        const float* __restrict__ rho, const float* __restrict__ Mg,
        const float* __restrict__ iSg, const float* __restrict__ theta,
        const int* __restrict__ times, const float* __restrict__ bows, float* acc){
  int t = blockIdx.y, vb = blockIdx.x, v0 = vb*120;
  __shared__ float aS[50*50];
  __shared__ float rS[50*120];
  __shared__ float tS[50*120];
  __shared__ float red[256];
  __shared__ int tmS[128];
  __shared__ int any;
  if (TID==0) any=0;
  __syncthreads();
  if (TID<128){ int tv = times[TID]; tmS[TID]=tv; if (tv==t) any=1; }
  __syncthreads();
  if (!any) return;
  float accl[25];
  #pragma unroll
  for (int j=0;j<25;j++) accl[j]=0.f;
  int ki=TID/24, vi=TID%24; bool act = TID<240;
  const float* aG = alphas + t*15000;
  for (int et=0; et<6; et++){
    for (int i=TID;i<2500;i+=256){ int k=i/50, e=i%50; aS[e*50+k]=aG[k*300+et*50+e]; }
    for (int i=TID;i<6000;i+=256){ int v=i/50, e=i%50; rS[e*120+v]=rho[(v0+v)*300+et*50+e]; }
    __syncthreads();
    if (act){
      for (int e=0;e<50;e++){
        const float* ap=&aS[e*50+ki*5];
        const float* rp=&rS[e*120+vi*5];
        float av[5], bv[5];
        #pragma unroll
        for (int j=0;j<5;j++){ av[j]=ap[j]; bv[j]=rp[j]; }
        #pragma unroll
        for (int j=0;j<5;j++)
          #pragma unroll
          for (int i2=0;i2<5;i2++) accl[j*5+i2] = fmaf(av[j],bv[i2],accl[j*5+i2]);
      }
    }
    __syncthreads();
  }
  if (act){
    #pragma unroll
    for (int j=0;j<5;j++){
      int k = ki*5+j;
      float mk = Mg[t*50+k], isk = iSg[t*50+k];
      #pragma unroll
      for (int i2=0;i2<5;i2++) tS[k*120 + vi*5+i2] = expf(accl[j*5+i2]-mk)*isk;
    }
  }
  __syncthreads();
  float local = 0.f;
  for (int bi=0;bi<128;bi++){
    if (tmS[bi]!=t) continue;
    if (TID<120){
      const float* th = theta + bi*50;
      float p = 0.f;
      #pragma unroll 10
      for (int k=0;k<50;k++) p = fmaf(th[k], tS[k*120+TID], p);
      local -= logf(p+1e-6f)*bows[bi*30000 + v0 + TID];
    }
  }
  red[TID]=local; __syncthreads();
  for (int s=128;s>0;s>>=1){ if (TID<s) red[TID]+=red[TID+s]; __syncthreads(); }
  if (TID==0) atomicAdd(acc+3, red[0]);
}

// ---------------- finalize ----------------
__global__ void k_final(const float* __restrict__ acc, const int* __restrict__ nd,
                        float* __restrict__ out){
  float coeff = (float)(*nd) / 128.0f;
  float nll = acc[3]*coeff;
  float klth = acc[2]*coeff;
  out[0] = nll + acc[0] + acc[1] + klth;
  out[1] = nll;
  out[2] = acc[0];
  out[3] = acc[1];
  out[4] = klth;
}

extern "C" void kernel_launch(void* const* d_in, const int* in_sizes, int n_in,
                              void* d_out, int out_size, void* d_ws, size_t ws_size,
                              hipStream_t stream) {
  (void)in_sizes; (void)n_in; (void)out_size; (void)ws_size;
  const float* bows  = (const float*)d_in[0];
  const float* nb    = (const float*)d_in[1];
  const int*   times = (const int*)d_in[2];
  const float* rnn   = (const float*)d_in[3];
  const int*   ndocs = (const int*)d_in[4];
  const float* eps_a = (const float*)d_in[5];
  const float* eps_e = (const float*)d_in[6];
  const float* eps_t = (const float*)d_in[7];
  const float* rho   = (const float*)d_in[8];
  const float* mqa   = (const float*)d_in[9];
  const float* lqa   = (const float*)d_in[10];
  const float* W1    = (const float*)d_in[11];
  const float* b1    = (const float*)d_in[12];
  const float* W2    = (const float*)d_in[13];
  const float* b2    = (const float*)d_in[14];
  const float* Wmu_t = (const float*)d_in[15];
  const float* bmu_t = (const float*)d_in[16];
  const float* Wls_t = (const float*)d_in[17];
  const float* bls_t = (const float*)d_in[18];
  const float* Wmap  = (const float*)d_in[19];
  const float* bmap  = (const float*)d_in[20];
  const float* Wih   = (const float*)d_in[21];
  const float* Whh   = (const float*)d_in[22];
  const float* bih   = (const float*)d_in[23];
  const float* bhh   = (const float*)d_in[24];
  const float* Wmu_e = (const float*)d_in[25];
  const float* bmu_e = (const float*)d_in[26];
  const float* Wls_e = (const float*)d_in[27];
  const float* bls_e = (const float*)d_in[28];
  float* out = (float*)d_out;

  float* w      = (float*)d_ws;
  float* acc    = w;                      // 8
  float* alphas = w + 8;                  // 900000
  float* im     = alphas + 900000;        // 12000
  float* outA   = im + 12000;             // 12000
  float* outB   = outA + 12000;           // 12000
  float* pre    = outB + 12000;           // 48000
  float* etas   = pre + 48000;            // 3000
  float* h1     = etas + 3000;            // 102400
  float* h2     = h1 + 102400;            // 102400
  float* muth   = h2 + 102400;            // 6400
  float* lsth   = muth + 6400;            // 6400
  float* theta  = lsth + 6400;            // 6400
  float* Mp     = theta + 6400;           // 750000
  float* Sp     = Mp + 750000;            // 750000
  float* Mg     = Sp + 750000;            // 3000
  float* iSg    = Mg + 3000;              // 3000  (total ~10.9 MB)

  k_zero<<<1,64,0,stream>>>(acc);
  k_alphas<<<3516,256,0,stream>>>(mqa, lqa, eps_a, alphas);
  k_klalpha<<<3516,256,0,stream>>>(mqa, lqa, alphas, acc);
  k_iminit<<<47,256,0,stream>>>(im, bmap);
  k_imgemm<<<dim3(47,8),256,0,stream>>>(rnn, Wmap, im);

  const float* x = im;
  float* bufs[2] = {outA, outB};
  for (int l=0;l<3;l++){
    float* o = bufs[l%2];
    k_pregates<<<dim3(60,4),256,0,stream>>>(x, Wih + l*160000, bih + l*800, bhh + l*800, pre);
    k_lstm<<<1,768,0,stream>>>(pre, Whh + l*160000, o);
    x = o;
  }
  const float* lstm_out = x;  // outA after 3 layers

  k_eta<<<1,256,0,stream>>>(lstm_out, Wmu_e, bmu_e, Wls_e, bls_e, eps_e, etas, acc);
  k_h1init<<<400,256,0,stream>>>(h1, b1);
  k_h1gemm<<<dim3(13,32),256,0,stream>>>(nb, times, etas, W1, h1);
  k_h2<<<dim3(128,4),256,0,stream>>>(h1, W2, b2, h2);
  k_muls<<<128,128,0,stream>>>(h2, Wmu_t, bmu_t, Wls_t, bls_t, muth, lsth);
  k_theta<<<128,64,0,stream>>>(muth, lsth, etas, times, eps_t, theta, acc);
  k_pass1<<<dim3(250,60),256,0,stream>>>(alphas, rho, Mp, Sp);
  k_msred<<<3000,256,0,stream>>>(Mp, Sp, Mg, iSg);
  k_pass2<<<dim3(250,60),256,0,stream>>>(alphas, rho, Mg, iSg, theta, times, bows, acc);
  k_final<<<1,1,0,stream>>>(acc, ndocs, out);
}

// Round 2
// 4298.570 us; speedup vs baseline: 1.7815x; 1.7815x over previous
//
#include <hip/hip_runtime.h>
#include <hip/hip_fp16.h>
#include <math.h>

#define TID ((int)threadIdx.x)

// dims: V=30000 K=50 E=300 T=60 B=128 TH=800 H=200 L=3
// beta GEMM tiling: NVB=235 v-blocks of 128 rows (30080 padded), t-split 4 x 15
#define NVB 235

static __device__ __forceinline__ float sigf(float x){ return 1.f/(1.f+expf(-x)); }

static __device__ __forceinline__ unsigned short f2bf(float f){
  unsigned u = __float_as_uint(f);
  unsigned r = (u + 0x7FFFu + ((u>>16)&1u)) >> 16;
  return (unsigned short)r;
}

typedef short v8ss __attribute__((ext_vector_type(8)));
typedef float v16f __attribute__((ext_vector_type(16)));
union I4BF { int4 i; v8ss s; };

// ---------------- init ----------------
__global__ void k_zero(float* acc){ if (TID<8) acc[TID]=0.f; }

// ---------------- alphas + kl_alpha ----------------
__global__ void k_alphas(const float* __restrict__ mqa, const float* __restrict__ lqa,
                         const float* __restrict__ eps, float* __restrict__ alphas){
  int i = blockIdx.x*256+TID; if (i>=900000) return;
  int t = i/15000, r = i%15000, k = r/300, e = r%300;
  int src = k*18000 + t*300 + e;
  float mu = mqa[src], ls = lqa[src];
  alphas[i] = mu + eps[i]*expf(0.5f*ls);
}

__global__ void k_klalpha(const float* __restrict__ mqa, const float* __restrict__ lqa,
                          const float* __restrict__ alphas, float* acc){
  __shared__ float red[256];
  int i = blockIdx.x*256+TID;
  float term = 0.f;
  if (i<900000){
    int t = i/15000, r = i%15000, k = r/300, e = r%300;
    int src = k*18000 + t*300 + e;
    float mu = mqa[src], ls = lqa[src];
    if (t==0){
      term = (expf(ls)+mu*mu)*(1.0f/(1.0f+1e-6f)) - 1.f - ls;
    } else {
      float d = mu - alphas[i-15000];
      term = (expf(ls)+d*d)*(1.0f/(0.005f+1e-6f)) - 1.f + logf(0.005f) - ls;
    }
  }
  red[TID]=term; __syncthreads();
  for (int s=128;s>0;s>>=1){ if (TID<s) red[TID]+=red[TID+s]; __syncthreads(); }
  if (TID==0) atomicAdd(acc+0, 0.5f*red[0]);
}

// ---------------- bf16 fragment prep for beta GEMM ----------------
// rho_f: per (r32 in [0,940), kstep in [0,19)): 64 lanes x 8 bf16
//   lane: v = r32*32 + (lane&31), e = kstep*16 + (lane>>5)*8 + j
__global__ void k_prep_rho(const float* __restrict__ rho, unsigned short* __restrict__ rho_f){
  int tid = blockIdx.x*256+TID;
  if (tid >= 940*19*64) return;
  int lane = tid & 63;
  int F = tid >> 6;
  int kstep = F % 19;
  int r32 = F / 19;
  int v = r32*32 + (lane & 31);
  int e0 = kstep*16 + ((lane>>5)<<3);
  unsigned short u[8];
  #pragma unroll
  for (int j=0;j<8;j++){
    int e = e0 + j;
    float val = (v < 30000 && e < 300) ? rho[v*300 + e] : 0.f;
    u[j] = f2bf(val);
  }
  int4 o;
  o.x = (int)u[0] | ((int)u[1]<<16);
  o.y = (int)u[2] | ((int)u[3]<<16);
  o.z = (int)u[4] | ((int)u[5]<<16);
  o.w = (int)u[6] | ((int)u[7]<<16);
  ((int4*)rho_f)[tid] = o;
}

// alpha_f: per (t, nt in [0,2), kstep): 64 lanes x 8 bf16
//   lane: k = nt*32 + (lane&31), e = kstep*16 + (lane>>5)*8 + j
__global__ void k_prep_alpha(const float* __restrict__ alphas, unsigned short* __restrict__ alpha_f){
  int tid = blockIdx.x*256+TID;
  if (tid >= 60*2*19*64) return;
  int lane = tid & 63;
  int F = tid >> 6;
  int kstep = F % 19;
  int tn = F / 19;
  int nt = tn % 2, t = tn / 2;
  int k = nt*32 + (lane & 31);
  int e0 = kstep*16 + ((lane>>5)<<3);
  unsigned short u[8];
  #pragma unroll
  for (int j=0;j<8;j++){
    int e = e0 + j;
    float val = (k < 50 && e < 300) ? alphas[t*15000 + k*300 + e] : 0.f;
    u[j] = f2bf(val);
  }
  int4 o;
  o.x = (int)u[0] | ((int)u[1]<<16);
  o.y = (int)u[2] | ((int)u[3]<<16);
  o.z = (int)u[4] | ((int)u[5]<<16);
  o.w = (int)u[6] | ((int)u[7]<<16);
  ((int4*)alpha_f)[tid] = o;
}

// ---------------- inp_map = rnn_inp @ Wmap.T + bmap ----------------
__global__ void k_iminit(float* __restrict__ im, const float* __restrict__ bmap){
  int i = blockIdx.x*256+TID; if (i<12000) im[i] = bmap[i%200];
}

__global__ void k_imgemm(const float* __restrict__ rnn, const float* __restrict__ Wmap,
                         float* __restrict__ im){
  int i = blockIdx.x*256+TID; if (i>=12000) return;
  int t = i%60, h = i/60;
  int k0 = blockIdx.y*3750;
  const float* rp = rnn + t*30000 + k0;
  const float* wp = Wmap + h*30000 + k0;
  float a = 0.f;
  #pragma unroll 4
  for (int c=0;c<3750;c++) a = fmaf(rp[c], wp[c], a);
  atomicAdd(&im[t*200+h], a);
}

// ---------------- LSTM pre-gates ----------------
__global__ void k_pregates(const float* __restrict__ x, const float* __restrict__ Wih,
                           const float* __restrict__ bih, const float* __restrict__ bhh,
                           float* __restrict__ pre){
  __shared__ float xS[200];
  int t = blockIdx.x;
  if (TID<200) xS[TID] = x[t*200+TID];
  __syncthreads();
  int r = blockIdx.y*256 + TID;
  if (r>=800) return;
  float a = bih[r] + bhh[r];
  const float* wp = Wih + r*200;
  #pragma unroll 4
  for (int c=0;c<200;c++) a = fmaf(wp[c], xS[c], a);
  pre[t*800+r] = a;
}

// ---------------- LSTM recurrent (single block; Whh in regs as f16) ----------------
__global__ __launch_bounds__(768,3) void k_lstm(const float* __restrict__ pre,
        const float* __restrict__ Whh, float* __restrict__ out){
  __shared__ __align__(16) float hs[200];
  __shared__ float cs[200];
  __shared__ float gsh[800];
  __shared__ float wext[32*201];
  for (int i=TID;i<6400;i+=768){ int r=i/200,c=i%200; wext[r*201+c]=Whh[(768+r)*200+c]; }
  __half2 w[100];
  {
    const float4* wr = reinterpret_cast<const float4*>(Whh + TID*200);
    #pragma unroll
    for (int i=0;i<50;i++){
      float4 v = wr[i];
      w[2*i]   = __halves2half2(__float2half_rn(v.x), __float2half_rn(v.y));
      w[2*i+1] = __halves2half2(__float2half_rn(v.z), __float2half_rn(v.w));
    }
  }
  if (TID<200){ hs[TID]=0.f; cs[TID]=0.f; }
  __syncthreads();
  for (int t=0;t<60;t++){
    float a = pre[t*800+TID];
    const float4* h4 = reinterpret_cast<const float4*>(hs);
    #pragma unroll
    for (int i=0;i<50;i++){
      float4 hv = h4[i];
      float2 p = __half22float2(w[2*i]);
      float2 q = __half22float2(w[2*i+1]);
      a = fmaf(p.x,hv.x,a); a = fmaf(p.y,hv.y,a);
      a = fmaf(q.x,hv.z,a); a = fmaf(q.y,hv.w,a);
    }
    gsh[TID] = a;
    if (TID<32){
      float a2 = pre[t*800+768+TID];
      const float* we = &wext[TID*201];
      #pragma unroll 4
      for (int c=0;c<200;c++) a2 = fmaf(we[c], hs[c], a2);
      gsh[768+TID] = a2;
    }
    __syncthreads();
    if (TID<200){
      float ii=gsh[TID], ff=gsh[200+TID], gg=gsh[400+TID], oo=gsh[600+TID];
      float c = sigf(ff)*cs[TID] + sigf(ii)*tanhf(gg);
      cs[TID]=c;
      float h = sigf(oo)*tanhf(c);
      hs[TID]=h;
      out[t*200+TID]=h;
    }
    __syncthreads();
  }
}

// ---------------- eta chain (single block) ----------------
__global__ void k_eta(const float* __restrict__ outF, const float* __restrict__ Wmu,
                      const float* __restrict__ bmu, const float* __restrict__ Wls,
                      const float* __restrict__ bls, const float* __restrict__ eps,
                      float* __restrict__ etas, float* acc){
  __shared__ __half wS[100*254];
  __shared__ float inp[256];
  __shared__ float pt[200];
  __shared__ float muS[64], lsS[64];
  for (int i=TID;i<12500;i+=256) wS[(i/250)*254 + (i%250)] = __float2half_rn(Wmu[i]);
  for (int i=TID;i<12500;i+=256) wS[(50+i/250)*254 + (i%250)] = __float2half_rn(Wls[i]);
  if (TID<50) inp[200+TID]=0.f;
  const float LOGD = logf(0.005f);
  float kacc = 0.f;
  __syncthreads();
  for (int t=0;t<60;t++){
    if (TID<200) inp[TID] = outF[t*200+TID];
    __syncthreads();
    if (TID<200){
      int rr = TID%100, hf = TID/100;
      const __half* wp = &wS[rr*254 + hf*125];
      const float* ip = &inp[hf*125];
      float s=0.f;
      for (int c=0;c<125;c++) s = fmaf(__half2float(wp[c]), ip[c], s);
      pt[TID]=s;
    }
    __syncthreads();
    if (TID<100){
      float v = pt[TID]+pt[TID+100];
      if (TID<50) muS[TID] = v + bmu[TID];
      else lsS[TID-50] = v + bls[TID-50];
    }
    __syncthreads();
    if (TID<64){
      float term=0.f;
      if (TID<50){
        float mu=muS[TID], ls=lsS[TID], ep=inp[200+TID];
        if (t==0) term = (expf(ls)+mu*mu)*(1.0f/(1.0f+1e-6f)) - 1.f - ls;
        else { float d=mu-ep; term = (expf(ls)+d*d)*(1.0f/(0.005f+1e-6f)) - 1.f + LOGD - ls; }
        float et = mu + eps[t*50+TID]*expf(0.5f*ls);
        etas[t*50+TID]=et;
        inp[200+TID]=et;
      }
      for (int o=32;o>0;o>>=1) term += __shfl_down(term,o);
      if (TID==0) kacc += 0.5f*term;
    }
    __syncthreads();
  }
  if (TID==0) atomicAdd(acc+1, kacc);
}

// ---------------- h1 = qt_in @ W1.T + b1 (atomic k-split GEMM) ----------------
__global__ void k_h1init(float* __restrict__ h1, const float* __restrict__ b1){
  int i = blockIdx.x*256+TID; if (i<102400) h1[i] = b1[i%800];
}

__global__ void k_h1gemm(const float* __restrict__ nb, const int* __restrict__ times,
                         const float* __restrict__ etas, const float* __restrict__ W1,
                         float* __restrict__ h1){
  __shared__ __align__(16) float As[16*132];
  __shared__ __align__(16) float Ws[16*68];
  __shared__ int tS[128];
  if (TID<128) tS[TID]=times[TID];
  int rt = blockIdx.x, sp = blockIdx.y;
  int kbeg = sp*940;
  int kend = (kbeg+940<30050)?(kbeg+940):30050;
  int b0 = (TID%32)*4, r0 = (TID/32)*8;
  float acc[32];
  #pragma unroll
  for (int j=0;j<32;j++) acc[j]=0.f;
  for (int kb=kbeg; kb<kend; kb+=16){
    __syncthreads();
    for (int i=TID;i<2048;i+=256){
      int b=i/16, kk=i%16, kg=kb+kk;
      float v=0.f;
      if (kg<kend){ v = (kg<30000)? nb[b*30000+kg] : etas[tS[b]*50 + (kg-30000)]; }
      As[kk*132+b]=v;
    }
    for (int i=TID;i<1024;i+=256){
      int r=i/16, kk=i%16, kg=kb+kk, rg=rt*64+r;
      float v=0.f;
      if (kg<kend && rg<800) v = W1[rg*30050+kg];
      Ws[kk*68+r]=v;
    }
    __syncthreads();
    #pragma unroll
    for (int kk=0;kk<16;kk++){
      float4 a4 = *reinterpret_cast<const float4*>(&As[kk*132+b0]);
      float4 w4 = *reinterpret_cast<const float4*>(&Ws[kk*68+r0]);
      float4 w5 = *reinterpret_cast<const float4*>(&Ws[kk*68+r0+4]);
      float aa[4]={a4.x,a4.y,a4.z,a4.w};
      float ww[8]={w4.x,w4.y,w4.z,w4.w,w5.x,w5.y,w5.z,w5.w};
      #pragma unroll
      for (int j=0;j<4;j++)
        #pragma unroll
        for (int i2=0;i2<8;i2++) acc[j*8+i2] = fmaf(aa[j], ww[i2], acc[j*8+i2]);
    }
  }
  #pragma unroll
  for (int j=0;j<4;j++){
    int b=b0+j;
    #pragma unroll
    for (int i2=0;i2<8;i2++){
      int rg = rt*64+r0+i2;
      if (rg<800) atomicAdd(&h1[b*800+rg], acc[j*8+i2]);
    }
  }
}

// ---------------- h2 = relu(relu(h1) @ W2.T + b2) ----------------
__global__ void k_h2(const float* __restrict__ h1, const float* __restrict__ W2,
                     const float* __restrict__ b2, float* __restrict__ h2){
  __shared__ float h1S[800];
  int b = blockIdx.x;
  for (int i=TID;i<800;i+=256) h1S[i] = fmaxf(h1[b*800+i], 0.f);
  __syncthreads();
  int r = blockIdx.y*256 + TID;
  if (r>=800) return;
  float a = b2[r];
  const float* wp = W2 + r*800;
  #pragma unroll 4
  for (int c=0;c<800;c++) a = fmaf(wp[c], h1S[c], a);
  h2[b*800+r] = fmaxf(a, 0.f);
}

// ---------------- mu_th / ls_th ----------------
__global__ void k_muls(const float* __restrict__ h2, const float* __restrict__ Wmu,
                       const float* __restrict__ bmu, const float* __restrict__ Wls,
                       const float* __restrict__ bls, float* __restrict__ muth,
                       float* __restrict__ lsth){
  __shared__ float hS[800];
  int b = blockIdx.x;
  for (int i=TID;i<800;i+=128) hS[i] = h2[b*800+i];
  __syncthreads();
  if (TID<50){
    float a = bmu[TID];
    const float* wp = Wmu + TID*800;
    #pragma unroll 4
    for (int c=0;c<800;c++) a = fmaf(wp[c], hS[c], a);
    muth[b*50+TID]=a;
  } else if (TID>=64 && TID<114){
    int r = TID-64;
    float a = bls[r];
    const float* wp = Wls + r*800;
    #pragma unroll 4
    for (int c=0;c<800;c++) a = fmaf(wp[c], hS[c], a);
    lsth[b*50+r]=a;
  }
}

// ---------------- theta + kl_theta ----------------
__global__ void k_theta(const float* __restrict__ muth, const float* __restrict__ lsth,
                        const float* __restrict__ etas, const int* __restrict__ times,
                        const float* __restrict__ epsth, float* __restrict__ theta,
                        float* acc){
  int b = blockIdx.x, k = TID;
  bool a = k<50;
  int tb = times[b];
  float mu=0.f, ls=0.f, etd=0.f, z=-INFINITY;
  if (a){
    mu = muth[b*50+k]; ls = lsth[b*50+k]; etd = etas[tb*50+k];
    z = mu + epsth[b*50+k]*expf(0.5f*ls);
  }
  float m=z;
  for (int o=32;o>0;o>>=1) m = fmaxf(m, __shfl_xor(m,o));
  float e = a ? expf(z-m) : 0.f;
  float s = e;
  for (int o=32;o>0;o>>=1) s += __shfl_xor(s,o);
  if (a) theta[b*50+k] = e/s;
  float term = a ? ((expf(ls)+(mu-etd)*(mu-etd))*(1.0f/(1.0f+1e-6f)) - 1.f - ls) : 0.f;
  for (int o=32;o>0;o>>=1) term += __shfl_xor(term,o);
  if (TID==0) atomicAdd(acc+2, 0.5f*term);
}

// ---------------- MFMA beta pass 1: per-(t,k) max / sumexp partials ----------------
// wave: 32 v-rows x 64 topic-cols; A (rho frags) register-resident across t-loop
__global__ __launch_bounds__(256,2) void k_mf1(const unsigned short* __restrict__ rho_f,
        const unsigned short* __restrict__ alpha_f,
        float* __restrict__ Mp, float* __restrict__ Sp){
  int vb = blockIdx.x, tg = blockIdx.y;
  int wid = TID>>6, lane = TID&63;
  int r32 = vb*4 + wid;
  const int4* ap = ((const int4*)rho_f) + (r32*19)*64 + lane;
  int4 a[19];
  #pragma unroll
  for (int ks=0;ks<19;ks++) a[ks] = ap[ks*64];
  __shared__ float redM[4][64];
  __shared__ float redS[4][64];
  int rowbase = vb*128 + wid*32 + ((lane>>5)<<2);
  for (int t = tg*15; t < tg*15+15; t++){
    v16f acc0, acc1;
    #pragma unroll
    for (int i=0;i<16;i++){ acc0[i]=0.f; acc1[i]=0.f; }
    const int4* bp = ((const int4*)alpha_f) + (t*38)*64 + lane;
    #pragma unroll
    for (int ks=0;ks<19;ks++){
      I4BF av, b0, b1;
      av.i = a[ks];
      b0.i = bp[ks*64];
      b1.i = bp[(19+ks)*64];
      acc0 = __builtin_amdgcn_mfma_f32_32x32x16_bf16(av.s, b0.s, acc0, 0,0,0);
      acc1 = __builtin_amdgcn_mfma_f32_32x32x16_bf16(av.s, b1.s, acc1, 0,0,0);
    }
    float m0=-INFINITY, m1=-INFINITY;
    #pragma unroll
    for (int r=0;r<16;r++){
      int v = rowbase + (r&3) + ((r>>2)<<3);
      if (v < 30000){ m0 = fmaxf(m0, acc0[r]); m1 = fmaxf(m1, acc1[r]); }
    }
    m0 = fmaxf(m0, __shfl_xor(m0, 32));
    m1 = fmaxf(m1, __shfl_xor(m1, 32));
    float s0=0.f, s1=0.f;
    #pragma unroll
    for (int r=0;r<16;r++){
      int v = rowbase + (r&3) + ((r>>2)<<3);
      if (v < 30000){ s0 += expf(acc0[r]-m0); s1 += expf(acc1[r]-m1); }
    }
    s0 += __shfl_xor(s0, 32);
    s1 += __shfl_xor(s1, 32);
    if (lane < 32){
      redM[wid][lane] = m0; redM[wid][lane+32] = m1;
      redS[wid][lane] = s0; redS[wid][lane+32] = s1;
    }
    __syncthreads();
    if (TID < 50){
      float M = redM[0][TID];
      #pragma unroll
      for (int w2=1; w2<4; w2++) M = fmaxf(M, redM[w2][TID]);
      float S = 0.f;
      #pragma unroll
      for (int w2=0; w2<4; w2++){
        float mw = redM[w2][TID];
        if (mw > -INFINITY) S += redS[w2][TID] * expf(mw - M);
      }
      Mp[(t*50+TID)*NVB + vb] = M;
      Sp[(t*50+TID)*NVB + vb] = S;
    }
    __syncthreads();
  }
}

// ---------------- reduce partials -> M, 1/S ----------------
__global__ void k_msred(const float* __restrict__ Mp, const float* __restrict__ Sp,
                        float* __restrict__ Mg, float* __restrict__ iSg){
  __shared__ float red[256];
  int row = blockIdx.x;
  float m = (TID<NVB) ? Mp[row*NVB+TID] : -INFINITY;
  red[TID]=m; __syncthreads();
  for (int s=128;s>0;s>>=1){ if (TID<s) red[TID]=fmaxf(red[TID],red[TID+s]); __syncthreads(); }
  float M = red[0]; __syncthreads();
  float sv = (TID<NVB) ? Sp[row*NVB+TID]*expf(m-M) : 0.f;
  red[TID]=sv; __syncthreads();
  for (int s=128;s>0;s>>=1){ if (TID<s) red[TID]+=red[TID+s]; __syncthreads(); }
  if (TID==0){ Mg[row]=M; iSg[row]=1.f/red[0]; }
}

// ---------------- MFMA beta pass 2: recompute, normalize, fuse nll ----------------
__global__ __launch_bounds__(256,2) void k_mf2(const unsigned short* __restrict__ rho_f,
        const unsigned short* __restrict__ alpha_f,
        const float* __restrict__ Mg, const float* __restrict__ iSg,
        const float* __restrict__ theta, const int* __restrict__ times,
        const float* __restrict__ bows, float* acc){
  __shared__ float thS[128*52];
  __shared__ float tileS[4][32*66];
  __shared__ int tS[128];
  __shared__ int cntS[64];
  int vb = blockIdx.x, tg = blockIdx.y;
  int wid = TID>>6, lane = TID&63;
  if (TID < 64) cntS[TID] = 0;
  __syncthreads();
  if (TID < 128){ int tv = times[TID]; tS[TID] = tv; atomicAdd(&cntS[tv], 1); }
  for (int i=TID; i<6400; i+=256){ int b=i/50, c=i%50; thS[b*52+c] = theta[i]; }
  int r32 = vb*4 + wid;
  const int4* ap = ((const int4*)rho_f) + (r32*19)*64 + lane;
  int4 a[19];
  #pragma unroll
  for (int ks=0;ks<19;ks++) a[ks] = ap[ks*64];
  __syncthreads();
  float local = 0.f;
  int rb32 = ((lane>>5)<<2);
  int c0 = lane&31, c1 = 32 + (lane&31);
  for (int t = tg*15; t < tg*15+15; t++){
    if (cntS[t] == 0) continue;
    v16f acc0, acc1;
    #pragma unroll
    for (int i=0;i<16;i++){ acc0[i]=0.f; acc1[i]=0.f; }
    const int4* bp = ((const int4*)alpha_f) + (t*38)*64 + lane;
    #pragma unroll
    for (int ks=0;ks<19;ks++){
      I4BF av, b0, b1;
      av.i = a[ks];
      b0.i = bp[ks*64];
      b1.i = bp[(19+ks)*64];
      acc0 = __builtin_amdgcn_mfma_f32_32x32x16_bf16(av.s, b0.s, acc0, 0,0,0);
      acc1 = __builtin_amdgcn_mfma_f32_32x32x16_bf16(av.s, b1.s, acc1, 0,0,0);
    }
    float M0 = Mg[t*50+c0], i0 = iSg[t*50+c0];
    float M1 = 0.f, i1 = 0.f;
    if (c1 < 50){ M1 = Mg[t*50+c1]; i1 = iSg[t*50+c1]; }
    float* tl = &tileS[wid][0];
    #pragma unroll
    for (int r=0;r<16;r++){
      int row = rb32 + (r&3) + ((r>>2)<<3);
      tl[row*66 + c0] = expf(acc0[r]-M0)*i0;
      if (c1 < 50) tl[row*66 + c1] = expf(acc1[r]-M1)*i1;
    }
    __syncthreads();
    for (int b=0;b<128;b++){
      if (tS[b] != t) continue;
      int row = lane&31;
      int v = vb*128 + wid*32 + row;
      const float* th = &thS[b*52 + (lane>>5)*25];
      const float* tp = &tl[row*66 + (lane>>5)*25];
      float mix = 0.f;
      #pragma unroll 5
      for (int c=0;c<25;c++) mix = fmaf(th[c], tp[c], mix);
      mix += __shfl_xor(mix, 32);
      if (lane < 32 && v < 30000)
        local -= logf(mix + 1e-6f) * bows[b*30000 + v];
    }
    __syncthreads();
  }
  for (int o=1;o<64;o<<=1) local += __shfl_xor(local, o);
  if (lane==0) atomicAdd(acc+3, local);
}

// ---------------- finalize ----------------
__global__ void k_final(const float* __restrict__ acc, const int* __restrict__ nd,
                        float* __restrict__ out){
  float coeff = (float)(*nd) / 128.0f;
  float nll = acc[3]*coeff;
  float klth = acc[2]*coeff;
  out[0] = nll + acc[0] + acc[1] + klth;
  out[1] = nll;
  out[2] = acc[0];
  out[3] = acc[1];
  out[4] = klth;
}

extern "C" void kernel_launch(void* const* d_in, const int* in_sizes, int n_in,
                              void* d_out, int out_size, void* d_ws, size_t ws_size,
                              hipStream_t stream) {
  (void)in_sizes; (void)n_in; (void)out_size; (void)ws_size;
  const float* bows  = (const float*)d_in[0];
  const float* nb    = (const float*)d_in[1];
  const int*   times = (const int*)d_in[2];
  const float* rnn   = (const float*)d_in[3];
  const int*   ndocs = (const int*)d_in[4];
  const float* eps_a = (const float*)d_in[5];
  const float* eps_e = (const float*)d_in[6];
  const float* eps_t = (const float*)d_in[7];
  const float* rho   = (const float*)d_in[8];
  const float* mqa   = (const float*)d_in[9];
  const float* lqa   = (const float*)d_in[10];
  const float* W1    = (const float*)d_in[11];
  const float* b1    = (const float*)d_in[12];
  const float* W2    = (const float*)d_in[13];
  const float* b2    = (const float*)d_in[14];
  const float* Wmu_t = (const float*)d_in[15];
  const float* bmu_t = (const float*)d_in[16];
  const float* Wls_t = (const float*)d_in[17];
  const float* bls_t = (const float*)d_in[18];
  const float* Wmap  = (const float*)d_in[19];
  const float* bmap  = (const float*)d_in[20];
  const float* Wih   = (const float*)d_in[21];
  const float* Whh   = (const float*)d_in[22];
  const float* bih   = (const float*)d_in[23];
  const float* bhh   = (const float*)d_in[24];
  const float* Wmu_e = (const float*)d_in[25];
  const float* bmu_e = (const float*)d_in[26];
  const float* Wls_e = (const float*)d_in[27];
  const float* bls_e = (const float*)d_in[28];
  float* out = (float*)d_out;

  float* w      = (float*)d_ws;
  float* acc    = w;                        // 8
  unsigned short* rho_f   = (unsigned short*)(w + 8);          // 940*19*64*8 us = 4,569,600 f
  unsigned short* alpha_f = (unsigned short*)(w + 8 + 4569600); // 2280*64*8 us = 583,680 f
  float* alphas = w + 8 + 4569600 + 583680; // 900000
  float* im     = alphas + 900000;          // 12000
  float* outA   = im + 12000;               // 12000
  float* outB   = outA + 12000;             // 12000
  float* pre    = outB + 12000;             // 48000
  float* etas   = pre + 48000;              // 3000
  float* h1     = etas + 3000;              // 102400
  float* h2     = h1 + 102400;              // 102400
  float* muth   = h2 + 102400;              // 6400
  float* lsth   = muth + 6400;              // 6400
  float* theta  = lsth + 6400;              // 6400
  float* Mp     = theta + 6400;             // 3000*235 = 705000
  float* Sp     = Mp + 705000;              // 705000
  float* Mg     = Sp + 705000;              // 3000
  float* iSg    = Mg + 3000;                // 3000   total ~31.1 MB

  k_zero<<<1,64,0,stream>>>(acc);
  k_alphas<<<3516,256,0,stream>>>(mqa, lqa, eps_a, alphas);
  k_klalpha<<<3516,256,0,stream>>>(mqa, lqa, alphas, acc);
  k_prep_rho<<<4465,256,0,stream>>>(rho, rho_f);
  k_prep_alpha<<<570,256,0,stream>>>(alphas, alpha_f);
  k_iminit<<<47,256,0,stream>>>(im, bmap);
  k_imgemm<<<dim3(47,8),256,0,stream>>>(rnn, Wmap, im);

  const float* x = im;
  float* bufs[2] = {outA, outB};
  for (int l=0;l<3;l++){
    float* o = bufs[l%2];
    k_pregates<<<dim3(60,4),256,0,stream>>>(x, Wih + l*160000, bih + l*800, bhh + l*800, pre);
    k_lstm<<<1,768,0,stream>>>(pre, Whh + l*160000, o);
    x = o;
  }
  const float* lstm_out = x;

  k_eta<<<1,256,0,stream>>>(lstm_out, Wmu_e, bmu_e, Wls_e, bls_e, eps_e, etas, acc);
  k_h1init<<<400,256,0,stream>>>(h1, b1);
  k_h1gemm<<<dim3(13,32),256,0,stream>>>(nb, times, etas, W1, h1);
  k_h2<<<dim3(128,4),256,0,stream>>>(h1, W2, b2, h2);
  k_muls<<<128,128,0,stream>>>(h2, Wmu_t, bmu_t, Wls_t, bls_t, muth, lsth);
  k_theta<<<128,64,0,stream>>>(muth, lsth, etas, times, eps_t, theta, acc);
  k_mf1<<<dim3(NVB,4),256,0,stream>>>(rho_f, alpha_f, Mp, Sp);
  k_msred<<<3000,256,0,stream>>>(Mp, Sp, Mg, iSg);
  k_mf2<<<dim3(NVB,4),256,0,stream>>>(rho_f, alpha_f, Mg, iSg, theta, times, bows, acc);
  k_final<<<1,1,0,stream>>>(acc, ndocs, out);
}

// Round 3
// 3635.969 us; speedup vs baseline: 2.1061x; 1.1822x over previous
//
#include <hip/hip_runtime.h>
#include <hip/hip_fp16.h>
#include <math.h>

#define TID ((int)threadIdx.x)

// dims: V=30000 K=50 E=300 T=60 B=128 TH=800 H=200 L=3
// beta GEMM tiling: NVB=235 v-blocks of 128 rows (30080 padded), t-split 4 x 15
#define NVB 235

static __device__ __forceinline__ float sigf(float x){ return 1.f/(1.f+expf(-x)); }

static __device__ __forceinline__ unsigned short f2bf(float f){
  unsigned u = __float_as_uint(f);
  unsigned r = (u + 0x7FFFu + ((u>>16)&1u)) >> 16;
  return (unsigned short)r;
}

typedef short v8ss __attribute__((ext_vector_type(8)));
typedef float v16f __attribute__((ext_vector_type(16)));
union I4BF { int4 i; v8ss s; };
union U16B { int4 i; __half2 h2[4]; };

#define REP25(M) M(0) M(1) M(2) M(3) M(4) M(5) M(6) M(7) M(8) M(9) M(10) M(11) \
                 M(12) M(13) M(14) M(15) M(16) M(17) M(18) M(19) M(20) M(21) M(22) M(23) M(24)

// ---------------- init ----------------
__global__ void k_zero(float* acc){ if (TID<8) acc[TID]=0.f; }

// ---------------- alphas + kl_alpha ----------------
__global__ void k_alphas(const float* __restrict__ mqa, const float* __restrict__ lqa,
                         const float* __restrict__ eps, float* __restrict__ alphas){
  int i = blockIdx.x*256+TID; if (i>=900000) return;
  int t = i/15000, r = i%15000, k = r/300, e = r%300;
  int src = k*18000 + t*300 + e;
  float mu = mqa[src], ls = lqa[src];
  alphas[i] = mu + eps[i]*expf(0.5f*ls);
}

__global__ void k_klalpha(const float* __restrict__ mqa, const float* __restrict__ lqa,
                          const float* __restrict__ alphas, float* acc){
  __shared__ float red[256];
  int i = blockIdx.x*256+TID;
  float term = 0.f;
  if (i<900000){
    int t = i/15000, r = i%15000, k = r/300, e = r%300;
    int src = k*18000 + t*300 + e;
    float mu = mqa[src], ls = lqa[src];
    if (t==0){
      term = (expf(ls)+mu*mu)*(1.0f/(1.0f+1e-6f)) - 1.f - ls;
    } else {
      float d = mu - alphas[i-15000];
      term = (expf(ls)+d*d)*(1.0f/(0.005f+1e-6f)) - 1.f + logf(0.005f) - ls;
    }
  }
  red[TID]=term; __syncthreads();
  for (int s=128;s>0;s>>=1){ if (TID<s) red[TID]+=red[TID+s]; __syncthreads(); }
  if (TID==0) atomicAdd(acc+0, 0.5f*red[0]);
}

// ---------------- bf16 fragment prep for beta GEMM ----------------
__global__ void k_prep_rho(const float* __restrict__ rho, unsigned short* __restrict__ rho_f){
  int tid = blockIdx.x*256+TID;
  if (tid >= 940*19*64) return;
  int lane = tid & 63;
  int F = tid >> 6;
  int kstep = F % 19;
  int r32 = F / 19;
  int v = r32*32 + (lane & 31);
  int e0 = kstep*16 + ((lane>>5)<<3);
  unsigned short u[8];
  #pragma unroll
  for (int j=0;j<8;j++){
    int e = e0 + j;
    float val = (v < 30000 && e < 300) ? rho[v*300 + e] : 0.f;
    u[j] = f2bf(val);
  }
  int4 o;
  o.x = (int)u[0] | ((int)u[1]<<16);
  o.y = (int)u[2] | ((int)u[3]<<16);
  o.z = (int)u[4] | ((int)u[5]<<16);
  o.w = (int)u[6] | ((int)u[7]<<16);
  ((int4*)rho_f)[tid] = o;
}

__global__ void k_prep_alpha(const float* __restrict__ alphas, unsigned short* __restrict__ alpha_f){
  int tid = blockIdx.x*256+TID;
  if (tid >= 60*2*19*64) return;
  int lane = tid & 63;
  int F = tid >> 6;
  int kstep = F % 19;
  int tn = F / 19;
  int nt = tn % 2, t = tn / 2;
  int k = nt*32 + (lane & 31);
  int e0 = kstep*16 + ((lane>>5)<<3);
  unsigned short u[8];
  #pragma unroll
  for (int j=0;j<8;j++){
    int e = e0 + j;
    float val = (k < 50 && e < 300) ? alphas[t*15000 + k*300 + e] : 0.f;
    u[j] = f2bf(val);
  }
  int4 o;
  o.x = (int)u[0] | ((int)u[1]<<16);
  o.y = (int)u[2] | ((int)u[3]<<16);
  o.z = (int)u[4] | ((int)u[5]<<16);
  o.w = (int)u[6] | ((int)u[7]<<16);
  ((int4*)alpha_f)[tid] = o;
}

// ---------------- Whh f32 -> f16 (3 layers, 480000 elems) ----------------
__global__ void k_prep_whh(const float* __restrict__ Whh, __half* __restrict__ WhhH){
  int i = blockIdx.x*256+TID;
  if (i<480000) WhhH[i] = __float2half_rn(Whh[i]);
}

// ---------------- inp_map = rnn_inp @ Wmap.T + bmap ----------------
__global__ void k_iminit(float* __restrict__ im, const float* __restrict__ bmap){
  int i = blockIdx.x*256+TID; if (i<12000) im[i] = bmap[i%200];
}

__global__ void k_imgemm(const float* __restrict__ rnn, const float* __restrict__ Wmap,
                         float* __restrict__ im){
  int i = blockIdx.x*256+TID; if (i>=12000) return;
  int t = i%60, h = i/60;
  int k0 = blockIdx.y*3750;
  const float* rp = rnn + t*30000 + k0;
  const float* wp = Wmap + h*30000 + k0;
  float a = 0.f;
  #pragma unroll 4
  for (int c=0;c<3750;c++) a = fmaf(rp[c], wp[c], a);
  atomicAdd(&im[t*200+h], a);
}

// ---------------- LSTM pre-gates ----------------
__global__ void k_pregates(const float* __restrict__ x, const float* __restrict__ Wih,
                           const float* __restrict__ bih, const float* __restrict__ bhh,
                           float* __restrict__ pre){
  __shared__ float xS[200];
  int t = blockIdx.x;
  if (TID<200) xS[TID] = x[t*200+TID];
  __syncthreads();
  int r = blockIdx.y*256 + TID;
  if (r>=800) return;
  float a = bih[r] + bhh[r];
  const float* wp = Wih + r*200;
  #pragma unroll 4
  for (int c=0;c<200;c++) a = fmaf(wp[c], xS[c], a);
  pre[t*800+r] = a;
}

// ---------------- LSTM recurrent: weights in 25 named int4 regs (f16) ----------------
// rows 0..767: one row per thread, 200-wide dot from registers.
// rows 768..799: threads 512..767, 8 threads/row x 25 cols, shfl-reduced.
__global__ __launch_bounds__(768,3) void k_lstm(const float* __restrict__ pre,
        const __half* __restrict__ WhhH, float* __restrict__ out){
  __shared__ __align__(16) float hsF[200];
  __shared__ float gsh[800];
  __shared__ __half wtH[32*200];
  for (int i=TID;i<6400;i+=768) wtH[i] = WhhH[768*200 + i];
  const int4* wrow = reinterpret_cast<const int4*>(WhhH + TID*200);
#define DECLW(n) int4 w##n = wrow[n];
  REP25(DECLW)
#undef DECLW
  float c_reg = 0.f;
  if (TID<200) hsF[TID]=0.f;
  int j = TID - 512;                    // tail worker index (>=0 for threads 512..767)
  int trow = (j>=0) ? (j>>3) : 0;       // 0..31
  int tseg = (j>=0) ? (j&7)*25 : 0;
  float p = pre[TID];
  __syncthreads();
  for (int t=0;t<60;t++){
    float pn = pre[((t<59)?(t+1):t)*800 + TID];
    float a0=0.f,a1=0.f,a2=0.f,a3=0.f;
    const float4* hs4 = reinterpret_cast<const float4*>(hsF);
#define DOTW(n) { U16B u; u.i = w##n; \
    float4 hA = hs4[2*(n)], hB = hs4[2*(n)+1]; \
    float2 q0=__half22float2(u.h2[0]), q1=__half22float2(u.h2[1]); \
    float2 q2=__half22float2(u.h2[2]), q3=__half22float2(u.h2[3]); \
    a0=fmaf(q0.x,hA.x,a0); a1=fmaf(q0.y,hA.y,a1); \
    a2=fmaf(q1.x,hA.z,a2); a3=fmaf(q1.y,hA.w,a3); \
    a0=fmaf(q2.x,hB.x,a0); a1=fmaf(q2.y,hB.y,a1); \
    a2=fmaf(q3.x,hB.z,a2); a3=fmaf(q3.y,hB.w,a3); }
    REP25(DOTW)
#undef DOTW
    gsh[TID] = a0+a1+a2+a3 + p;
    if (j>=0){
      float pa = 0.f;
      const __half* wt = &wtH[trow*200 + tseg];
      const float* hp = &hsF[tseg];
      #pragma unroll
      for (int c2=0;c2<25;c2++) pa = fmaf(__half2float(wt[c2]), hp[c2], pa);
      pa += __shfl_down(pa,4); pa += __shfl_down(pa,2); pa += __shfl_down(pa,1);
      if ((j&7)==0) gsh[768+trow] = pa + pre[t*800+768+trow];
    }
    p = pn;
    __syncthreads();
    if (TID<200){
      float ii=gsh[TID], ff=gsh[200+TID], gg=gsh[400+TID], oo=gsh[600+TID];
      float c = sigf(ff)*c_reg + sigf(ii)*tanhf(gg);
      c_reg = c;
      float h = sigf(oo)*tanhf(c);
      hsF[TID]=h;
      out[t*200+TID]=h;
    }
    __syncthreads();
  }
}

// ---------------- eta chain (single block) ----------------
__global__ void k_eta(const float* __restrict__ outF, const float* __restrict__ Wmu,
                      const float* __restrict__ bmu, const float* __restrict__ Wls,
                      const float* __restrict__ bls, const float* __restrict__ eps,
                      float* __restrict__ etas, float* acc){
  __shared__ __half wS[100*254];
  __shared__ float inp[256];
  __shared__ float pt[200];
  __shared__ float muS[64], lsS[64];
  for (int i=TID;i<12500;i+=256) wS[(i/250)*254 + (i%250)] = __float2half_rn(Wmu[i]);
  for (int i=TID;i<12500;i+=256) wS[(50+i/250)*254 + (i%250)] = __float2half_rn(Wls[i]);
  if (TID<50) inp[200+TID]=0.f;
  const float LOGD = logf(0.005f);
  float kacc = 0.f;
  __syncthreads();
  for (int t=0;t<60;t++){
    if (TID<200) inp[TID] = outF[t*200+TID];
    __syncthreads();
    if (TID<200){
      int rr = TID%100, hf = TID/100;
      const __half* wp = &wS[rr*254 + hf*125];
      const float* ip = &inp[hf*125];
      float s=0.f;
      for (int c=0;c<125;c++) s = fmaf(__half2float(wp[c]), ip[c], s);
      pt[TID]=s;
    }
    __syncthreads();
    if (TID<100){
      float v = pt[TID]+pt[TID+100];
      if (TID<50) muS[TID] = v + bmu[TID];
      else lsS[TID-50] = v + bls[TID-50];
    }
    __syncthreads();
    if (TID<64){
      float term=0.f;
      if (TID<50){
        float mu=muS[TID], ls=lsS[TID], ep=inp[200+TID];
        if (t==0) term = (expf(ls)+mu*mu)*(1.0f/(1.0f+1e-6f)) - 1.f - ls;
        else { float d=mu-ep; term = (expf(ls)+d*d)*(1.0f/(0.005f+1e-6f)) - 1.f + LOGD - ls; }
        float et = mu + eps[t*50+TID]*expf(0.5f*ls);
        etas[t*50+TID]=et;
        inp[200+TID]=et;
      }
      for (int o=32;o>0;o>>=1) term += __shfl_down(term,o);
      if (TID==0) kacc += 0.5f*term;
    }
    __syncthreads();
  }
  if (TID==0) atomicAdd(acc+1, kacc);
}

// ---------------- h1 = qt_in @ W1.T + b1 (atomic k-split GEMM) ----------------
__global__ void k_h1init(float* __restrict__ h1, const float* __restrict__ b1){
  int i = blockIdx.x*256+TID; if (i<102400) h1[i] = b1[i%800];
}

__global__ void k_h1gemm(const float* __restrict__ nb, const int* __restrict__ times,
                         const float* __restrict__ etas, const float* __restrict__ W1,
                         float* __restrict__ h1){
  __shared__ __align__(16) float As[16*132];
  __shared__ __align__(16) float Ws[16*68];
  __shared__ int tS[128];
  if (TID<128) tS[TID]=times[TID];
  int rt = blockIdx.x, sp = blockIdx.y;
  int kbeg = sp*940;
  int kend = (kbeg+940<30050)?(kbeg+940):30050;
  int b0 = (TID%32)*4, r0 = (TID/32)*8;
  float acc[32];
  #pragma unroll
  for (int j=0;j<32;j++) acc[j]=0.f;
  for (int kb=kbeg; kb<kend; kb+=16){
    __syncthreads();
    for (int i=TID;i<2048;i+=256){
      int b=i/16, kk=i%16, kg=kb+kk;
      float v=0.f;
      if (kg<kend){ v = (kg<30000)? nb[b*30000+kg] : etas[tS[b]*50 + (kg-30000)]; }
      As[kk*132+b]=v;
    }
    for (int i=TID;i<1024;i+=256){
      int r=i/16, kk=i%16, kg=kb+kk, rg=rt*64+r;
      float v=0.f;
      if (kg<kend && rg<800) v = W1[rg*30050+kg];
      Ws[kk*68+r]=v;
    }
    __syncthreads();
    #pragma unroll
    for (int kk=0;kk<16;kk++){
      float4 a4 = *reinterpret_cast<const float4*>(&As[kk*132+b0]);
      float4 w4 = *reinterpret_cast<const float4*>(&Ws[kk*68+r0]);
      float4 w5 = *reinterpret_cast<const float4*>(&Ws[kk*68+r0+4]);
      float aa[4]={a4.x,a4.y,a4.z,a4.w};
      float ww[8]={w4.x,w4.y,w4.z,w4.w,w5.x,w5.y,w5.z,w5.w};
      #pragma unroll
      for (int j=0;j<4;j++)
        #pragma unroll
        for (int i2=0;i2<8;i2++) acc[j*8+i2] = fmaf(aa[j], ww[i2], acc[j*8+i2]);
    }
  }
  #pragma unroll
  for (int j=0;j<4;j++){
    int b=b0+j;
    #pragma unroll
    for (int i2=0;i2<8;i2++){
      int rg = rt*64+r0+i2;
      if (rg<800) atomicAdd(&h1[b*800+rg], acc[j*8+i2]);
    }
  }
}

// ---------------- h2 = relu(relu(h1) @ W2.T + b2) ----------------
__global__ void k_h2(const float* __restrict__ h1, const float* __restrict__ W2,
                     const float* __restrict__ b2, float* __restrict__ h2){
  __shared__ float h1S[800];
  int b = blockIdx.x;
  for (int i=TID;i<800;i+=256) h1S[i] = fmaxf(h1[b*800+i], 0.f);
  __syncthreads();
  int r = blockIdx.y*256 + TID;
  if (r>=800) return;
  float a = b2[r];
  const float* wp = W2 + r*800;
  #pragma unroll 4
  for (int c=0;c<800;c++) a = fmaf(wp[c], h1S[c], a);
  h2[b*800+r] = fmaxf(a, 0.f);
}

// ---------------- mu_th / ls_th ----------------
__global__ void k_muls(const float* __restrict__ h2, const float* __restrict__ Wmu,
                       const float* __restrict__ bmu, const float* __restrict__ Wls,
                       const float* __restrict__ bls, float* __restrict__ muth,
                       float* __restrict__ lsth){
  __shared__ float hS[800];
  int b = blockIdx.x;
  for (int i=TID;i<800;i+=128) hS[i] = h2[b*800+i];
  __syncthreads();
  if (TID<50){
    float a = bmu[TID];
    const float* wp = Wmu + TID*800;
    #pragma unroll 4
    for (int c=0;c<800;c++) a = fmaf(wp[c], hS[c], a);
    muth[b*50+TID]=a;
  } else if (TID>=64 && TID<114){
    int r = TID-64;
    float a = bls[r];
    const float* wp = Wls + r*800;
    #pragma unroll 4
    for (int c=0;c<800;c++) a = fmaf(wp[c], hS[c], a);
    lsth[b*50+r]=a;
  }
}

// ---------------- theta + kl_theta ----------------
__global__ void k_theta(const float* __restrict__ muth, const float* __restrict__ lsth,
                        const float* __restrict__ etas, const int* __restrict__ times,
                        const float* __restrict__ epsth, float* __restrict__ theta,
                        float* acc){
  int b = blockIdx.x, k = TID;
  bool a = k<50;
  int tb = times[b];
  float mu=0.f, ls=0.f, etd=0.f, z=-INFINITY;
  if (a){
    mu = muth[b*50+k]; ls = lsth[b*50+k]; etd = etas[tb*50+k];
    z = mu + epsth[b*50+k]*expf(0.5f*ls);
  }
  float m=z;
  for (int o=32;o>0;o>>=1) m = fmaxf(m, __shfl_xor(m,o));
  float e = a ? expf(z-m) : 0.f;
  float s = e;
  for (int o=32;o>0;o>>=1) s += __shfl_xor(s,o);
  if (a) theta[b*50+k] = e/s;
  float term = a ? ((expf(ls)+(mu-etd)*(mu-etd))*(1.0f/(1.0f+1e-6f)) - 1.f - ls) : 0.f;
  for (int o=32;o>0;o>>=1) term += __shfl_xor(term,o);
  if (TID==0) atomicAdd(acc+2, 0.5f*term);
}

// ---------------- MFMA beta pass 1 ----------------
__global__ __launch_bounds__(256,2) void k_mf1(const unsigned short* __restrict__ rho_f,
        const unsigned short* __restrict__ alpha_f,
        float* __restrict__ Mp, float* __restrict__ Sp){
  int vb = blockIdx.x, tg = blockIdx.y;
  int wid = TID>>6, lane = TID&63;
  int r32 = vb*4 + wid;
  const int4* ap = ((const int4*)rho_f) + (r32*19)*64 + lane;
  int4 a[19];
  #pragma unroll
  for (int ks=0;ks<19;ks++) a[ks] = ap[ks*64];
  __shared__ float redM[4][64];
  __shared__ float redS[4][64];
  int rowbase = vb*128 + wid*32 + ((lane>>5)<<2);
  for (int t = tg*15; t < tg*15+15; t++){
    v16f acc0, acc1;
    #pragma unroll
    for (int i=0;i<16;i++){ acc0[i]=0.f; acc1[i]=0.f; }
    const int4* bp = ((const int4*)alpha_f) + (t*38)*64 + lane;
    #pragma unroll
    for (int ks=0;ks<19;ks++){
      I4BF av, b0, b1;
      av.i = a[ks];
      b0.i = bp[ks*64];
      b1.i = bp[(19+ks)*64];
      acc0 = __builtin_amdgcn_mfma_f32_32x32x16_bf16(av.s, b0.s, acc0, 0,0,0);
      acc1 = __builtin_amdgcn_mfma_f32_32x32x16_bf16(av.s, b1.s, acc1, 0,0,0);
    }
    float m0=-INFINITY, m1=-INFINITY;
    #pragma unroll
    for (int r=0;r<16;r++){
      int v = rowbase + (r&3) + ((r>>2)<<3);
      if (v < 30000){ m0 = fmaxf(m0, acc0[r]); m1 = fmaxf(m1, acc1[r]); }
    }
    m0 = fmaxf(m0, __shfl_xor(m0, 32));
    m1 = fmaxf(m1, __shfl_xor(m1, 32));
    float s0=0.f, s1=0.f;
    #pragma unroll
    for (int r=0;r<16;r++){
      int v = rowbase + (r&3) + ((r>>2)<<3);
      if (v < 30000){ s0 += expf(acc0[r]-m0); s1 += expf(acc1[r]-m1); }
    }
    s0 += __shfl_xor(s0, 32);
    s1 += __shfl_xor(s1, 32);
    if (lane < 32){
      redM[wid][lane] = m0; redM[wid][lane+32] = m1;
      redS[wid][lane] = s0; redS[wid][lane+32] = s1;
    }
    __syncthreads();
    if (TID < 50){
      float M = redM[0][TID];
      #pragma unroll
      for (int w2=1; w2<4; w2++) M = fmaxf(M, redM[w2][TID]);
      float S = 0.f;
      #pragma unroll
      for (int w2=0; w2<4; w2++){
        float mw = redM[w2][TID];
        if (mw > -INFINITY) S += redS[w2][TID] * expf(mw - M);
      }
      Mp[(t*50+TID)*NVB + vb] = M;
      Sp[(t*50+TID)*NVB + vb] = S;
    }
    __syncthreads();
  }
}

// ---------------- reduce partials -> M, 1/S ----------------
__global__ void k_msred(const float* __restrict__ Mp, const float* __restrict__ Sp,
                        float* __restrict__ Mg, float* __restrict__ iSg){
  __shared__ float red[256];
  int row = blockIdx.x;
  float m = (TID<NVB) ? Mp[row*NVB+TID] : -INFINITY;
  red[TID]=m; __syncthreads();
  for (int s=128;s>0;s>>=1){ if (TID<s) red[TID]=fmaxf(red[TID],red[TID+s]); __syncthreads(); }
  float M = red[0]; __syncthreads();
  float sv = (TID<NVB) ? Sp[row*NVB+TID]*expf(m-M) : 0.f;
  red[TID]=sv; __syncthreads();
  for (int s=128;s>0;s>>=1){ if (TID<s) red[TID]+=red[TID+s]; __syncthreads(); }
  if (TID==0){ Mg[row]=M; iSg[row]=1.f/red[0]; }
}

// ---------------- MFMA beta pass 2: recompute, normalize, fuse nll ----------------
__global__ __launch_bounds__(256,2) void k_mf2(const unsigned short* __restrict__ rho_f,
        const unsigned short* __restrict__ alpha_f,
        const float* __restrict__ Mg, const float* __restrict__ iSg,
        const float* __restrict__ theta, const int* __restrict__ times,
        const float* __restrict__ bows, float* acc){
  __shared__ float thS[128*52];
  __shared__ float tileS[4][32*66];
  __shared__ int tS[128];
  __shared__ int cntS[64];
  int vb = blockIdx.x, tg = blockIdx.y;
  int wid = TID>>6, lane = TID&63;
  if (TID < 64) cntS[TID] = 0;
  __syncthreads();
  if (TID < 128){ int tv = times[TID]; tS[TID] = tv; atomicAdd(&cntS[tv], 1); }
  for (int i=TID; i<6400; i+=256){ int b=i/50, c=i%50; thS[b*52+c] = theta[i]; }
  int r32 = vb*4 + wid;
  const int4* ap = ((const int4*)rho_f) + (r32*19)*64 + lane;
  int4 a[19];
  #pragma unroll
  for (int ks=0;ks<19;ks++) a[ks] = ap[ks*64];
  __syncthreads();
  float local = 0.f;
  int rb32 = ((lane>>5)<<2);
  int c0 = lane&31, c1 = 32 + (lane&31);
  for (int t = tg*15; t < tg*15+15; t++){
    if (cntS[t] == 0) continue;
    v16f acc0, acc1;
    #pragma unroll
    for (int i=0;i<16;i++){ acc0[i]=0.f; acc1[i]=0.f; }
    const int4* bp = ((const int4*)alpha_f) + (t*38)*64 + lane;
    #pragma unroll
    for (int ks=0;ks<19;ks++){
      I4BF av, b0, b1;
      av.i = a[ks];
      b0.i = bp[ks*64];
      b1.i = bp[(19+ks)*64];
      acc0 = __builtin_amdgcn_mfma_f32_32x32x16_bf16(av.s, b0.s, acc0, 0,0,0);
      acc1 = __builtin_amdgcn_mfma_f32_32x32x16_bf16(av.s, b1.s, acc1, 0,0,0);
    }
    float M0 = Mg[t*50+c0], i0 = iSg[t*50+c0];
    float M1 = 0.f, i1 = 0.f;
    if (c1 < 50){ M1 = Mg[t*50+c1]; i1 = iSg[t*50+c1]; }
    float* tl = &tileS[wid][0];
    #pragma unroll
    for (int r=0;r<16;r++){
      int row = rb32 + (r&3) + ((r>>2)<<3);
      tl[row*66 + c0] = expf(acc0[r]-M0)*i0;
      if (c1 < 50) tl[row*66 + c1] = expf(acc1[r]-M1)*i1;
    }
    __syncthreads();
    for (int b=0;b<128;b++){
      if (tS[b] != t) continue;
      int row = lane&31;
      int v = vb*128 + wid*32 + row;
      const float* th = &thS[b*52 + (lane>>5)*25];
      const float* tp = &tl[row*66 + (lane>>5)*25];
      float mix = 0.f;
      #pragma unroll 5
      for (int c=0;c<25;c++) mix = fmaf(th[c], tp[c], mix);
      mix += __shfl_xor(mix, 32);
      if (lane < 32 && v < 30000)
        local -= logf(mix + 1e-6f) * bows[b*30000 + v];
    }
    __syncthreads();
  }
  for (int o=1;o<64;o<<=1) local += __shfl_xor(local, o);
  if (lane==0) atomicAdd(acc+3, local);
}

// ---------------- finalize ----------------
__global__ void k_final(const float* __restrict__ acc, const int* __restrict__ nd,
                        float* __restrict__ out){
  float coeff = (float)(*nd) / 128.0f;
  float nll = acc[3]*coeff;
  float klth = acc[2]*coeff;
  out[0] = nll + acc[0] + acc[1] + klth;
  out[1] = nll;
  out[2] = acc[0];
  out[3] = acc[1];
  out[4] = klth;
}

extern "C" void kernel_launch(void* const* d_in, const int* in_sizes, int n_in,
                              void* d_out, int out_size, void* d_ws, size_t ws_size,
                              hipStream_t stream) {
  (void)in_sizes; (void)n_in; (void)out_size; (void)ws_size;
  const float* bows  = (const float*)d_in[0];
  const float* nb    = (const float*)d_in[1];
  const int*   times = (const int*)d_in[2];
  const float* rnn   = (const float*)d_in[3];
  const int*   ndocs = (const int*)d_in[4];
  const float* eps_a = (const float*)d_in[5];
  const float* eps_e = (const float*)d_in[6];
  const float* eps_t = (const float*)d_in[7];
  const float* rho   = (const float*)d_in[8];
  const float* mqa   = (const float*)d_in[9];
  const float* lqa   = (const float*)d_in[10];
  const float* W1    = (const float*)d_in[11];
  const float* b1    = (const float*)d_in[12];
  const float* W2    = (const float*)d_in[13];
  const float* b2    = (const float*)d_in[14];
  const float* Wmu_t = (const float*)d_in[15];
  const float* bmu_t = (const float*)d_in[16];
  const float* Wls_t = (const float*)d_in[17];
  const float* bls_t = (const float*)d_in[18];
  const float* Wmap  = (const float*)d_in[19];
  const float* bmap  = (const float*)d_in[20];
  const float* Wih   = (const float*)d_in[21];
  const float* Whh   = (const float*)d_in[22];
  const float* bih   = (const float*)d_in[23];
  const float* bhh   = (const float*)d_in[24];
  const float* Wmu_e = (const float*)d_in[25];
  const float* bmu_e = (const float*)d_in[26];
  const float* Wls_e = (const float*)d_in[27];
  const float* bls_e = (const float*)d_in[28];
  float* out = (float*)d_out;

  float* w      = (float*)d_ws;
  float* acc    = w;                        // 8
  unsigned short* rho_f   = (unsigned short*)(w + 8);           // 4,569,600 f
  unsigned short* alpha_f = (unsigned short*)(w + 8 + 4569600); // 583,680 f
  float* alphas = w + 8 + 4569600 + 583680; // 900000
  float* im     = alphas + 900000;          // 12000
  float* outA   = im + 12000;               // 12000
  float* outB   = outA + 12000;             // 12000
  float* pre    = outB + 12000;             // 48000
  float* etas   = pre + 48000;              // 3000
  float* h1     = etas + 3000;              // 102400
  float* h2     = h1 + 102400;              // 102400
  float* muth   = h2 + 102400;              // 6400
  float* lsth   = muth + 6400;              // 6400
  float* theta  = lsth + 6400;              // 6400
  float* Mp     = theta + 6400;             // 705000
  float* Sp     = Mp + 705000;              // 705000
  float* Mg     = Sp + 705000;              // 3000
  float* iSg    = Mg + 3000;                // 3000
  __half* whhH  = (__half*)(iSg + 3000);    // 480000 halves = 240000 f; total ~32 MB

  k_zero<<<1,64,0,stream>>>(acc);
  k_alphas<<<3516,256,0,stream>>>(mqa, lqa, eps_a, alphas);
  k_klalpha<<<3516,256,0,stream>>>(mqa, lqa, alphas, acc);
  k_prep_rho<<<4465,256,0,stream>>>(rho, rho_f);
  k_prep_alpha<<<570,256,0,stream>>>(alphas, alpha_f);
  k_prep_whh<<<1875,256,0,stream>>>(Whh, whhH);
  k_iminit<<<47,256,0,stream>>>(im, bmap);
  k_imgemm<<<dim3(47,8),256,0,stream>>>(rnn, Wmap, im);

  const float* x = im;
  float* bufs[2] = {outA, outB};
  for (int l=0;l<3;l++){
    float* o = bufs[l%2];
    k_pregates<<<dim3(60,4),256,0,stream>>>(x, Wih + l*160000, bih + l*800, bhh + l*800, pre);
    k_lstm<<<1,768,0,stream>>>(pre, whhH + l*160000, o);
    x = o;
  }
  const float* lstm_out = x;

  k_eta<<<1,256,0,stream>>>(lstm_out, Wmu_e, bmu_e, Wls_e, bls_e, eps_e, etas, acc);
  k_h1init<<<400,256,0,stream>>>(h1, b1);
  k_h1gemm<<<dim3(13,32),256,0,stream>>>(nb, times, etas, W1, h1);
  k_h2<<<dim3(128,4),256,0,stream>>>(h1, W2, b2, h2);
  k_muls<<<128,128,0,stream>>>(h2, Wmu_t, bmu_t, Wls_t, bls_t, muth, lsth);
  k_theta<<<128,64,0,stream>>>(muth, lsth, etas, times, eps_t, theta, acc);
  k_mf1<<<dim3(NVB,4),256,0,stream>>>(rho_f, alpha_f, Mp, Sp);
  k_msred<<<3000,256,0,stream>>>(Mp, Sp, Mg, iSg);
  k_mf2<<<dim3(NVB,4),256,0,stream>>>(rho_f, alpha_f, Mg, iSg, theta, times, bows, acc);
  k_final<<<1,1,0,stream>>>(acc, ndocs, out);
}

// Round 4
// 3269.842 us; speedup vs baseline: 2.3419x; 1.1120x over previous
//
#include <hip/hip_runtime.h>
#include <hip/hip_fp16.h>
#include <math.h>

#define TID ((int)threadIdx.x)

// dims: V=30000 K=50 E=300 T=60 B=128 TH=800 H=200 L=3
// beta GEMM tiling: NVB=235 v-blocks of 128 rows (30080 padded), t-split 4 x 15
#define NVB 235

static __device__ __forceinline__ float sigf(float x){ return 1.f/(1.f+expf(-x)); }

static __device__ __forceinline__ unsigned short f2bf(float f){
  unsigned u = __float_as_uint(f);
  unsigned r = (u + 0x7FFFu + ((u>>16)&1u)) >> 16;
  return (unsigned short)r;
}

typedef short v8ss __attribute__((ext_vector_type(8)));
typedef float v16f __attribute__((ext_vector_type(16)));
union I4BF { int4 i; v8ss s; };
union U16B { int4 i; __half2 h2[4]; };

#define REP25(M) M(0) M(1) M(2) M(3) M(4) M(5) M(6) M(7) M(8) M(9) M(10) M(11) \
                 M(12) M(13) M(14) M(15) M(16) M(17) M(18) M(19) M(20) M(21) M(22) M(23) M(24)

// ---------------- init ----------------
__global__ void k_zero(float* acc){ if (TID<8) acc[TID]=0.f; }

// ---------------- alphas + kl_alpha ----------------
__global__ void k_alphas(const float* __restrict__ mqa, const float* __restrict__ lqa,
                         const float* __restrict__ eps, float* __restrict__ alphas){
  int i = blockIdx.x*256+TID; if (i>=900000) return;
  int t = i/15000, r = i%15000, k = r/300, e = r%300;
  int src = k*18000 + t*300 + e;
  float mu = mqa[src], ls = lqa[src];
  alphas[i] = mu + eps[i]*expf(0.5f*ls);
}

__global__ void k_klalpha(const float* __restrict__ mqa, const float* __restrict__ lqa,
                          const float* __restrict__ alphas, float* acc){
  __shared__ float red[256];
  int i = blockIdx.x*256+TID;
  float term = 0.f;
  if (i<900000){
    int t = i/15000, r = i%15000, k = r/300, e = r%300;
    int src = k*18000 + t*300 + e;
    float mu = mqa[src], ls = lqa[src];
    if (t==0){
      term = (expf(ls)+mu*mu)*(1.0f/(1.0f+1e-6f)) - 1.f - ls;
    } else {
      float d = mu - alphas[i-15000];
      term = (expf(ls)+d*d)*(1.0f/(0.005f+1e-6f)) - 1.f + logf(0.005f) - ls;
    }
  }
  red[TID]=term; __syncthreads();
  for (int s=128;s>0;s>>=1){ if (TID<s) red[TID]+=red[TID+s]; __syncthreads(); }
  if (TID==0) atomicAdd(acc+0, 0.5f*red[0]);
}

// ---------------- bf16 fragment prep for beta GEMM ----------------
__global__ void k_prep_rho(const float* __restrict__ rho, unsigned short* __restrict__ rho_f){
  int tid = blockIdx.x*256+TID;
  if (tid >= 940*19*64) return;
  int lane = tid & 63;
  int F = tid >> 6;
  int kstep = F % 19;
  int r32 = F / 19;
  int v = r32*32 + (lane & 31);
  int e0 = kstep*16 + ((lane>>5)<<3);
  unsigned short u[8];
  #pragma unroll
  for (int j=0;j<8;j++){
    int e = e0 + j;
    float val = (v < 30000 && e < 300) ? rho[v*300 + e] : 0.f;
    u[j] = f2bf(val);
  }
  int4 o;
  o.x = (int)u[0] | ((int)u[1]<<16);
  o.y = (int)u[2] | ((int)u[3]<<16);
  o.z = (int)u[4] | ((int)u[5]<<16);
  o.w = (int)u[6] | ((int)u[7]<<16);
  ((int4*)rho_f)[tid] = o;
}

__global__ void k_prep_alpha(const float* __restrict__ alphas, unsigned short* __restrict__ alpha_f){
  int tid = blockIdx.x*256+TID;
  if (tid >= 60*2*19*64) return;
  int lane = tid & 63;
  int F = tid >> 6;
  int kstep = F % 19;
  int tn = F / 19;
  int nt = tn % 2, t = tn / 2;
  int k = nt*32 + (lane & 31);
  int e0 = kstep*16 + ((lane>>5)<<3);
  unsigned short u[8];
  #pragma unroll
  for (int j=0;j<8;j++){
    int e = e0 + j;
    float val = (k < 50 && e < 300) ? alphas[t*15000 + k*300 + e] : 0.f;
    u[j] = f2bf(val);
  }
  int4 o;
  o.x = (int)u[0] | ((int)u[1]<<16);
  o.y = (int)u[2] | ((int)u[3]<<16);
  o.z = (int)u[4] | ((int)u[5]<<16);
  o.w = (int)u[6] | ((int)u[7]<<16);
  ((int4*)alpha_f)[tid] = o;
}

// ---------------- Whh f32 -> f16 (3 layers, 480000 elems) ----------------
__global__ void k_prep_whh(const float* __restrict__ Whh, __half* __restrict__ WhhH){
  int i = blockIdx.x*256+TID;
  if (i<480000) WhhH[i] = __float2half_rn(Whh[i]);
}

// ---------------- inp_map = rnn_inp @ Wmap.T + bmap ----------------
__global__ void k_iminit(float* __restrict__ im, const float* __restrict__ bmap){
  int i = blockIdx.x*256+TID; if (i<12000) im[i] = bmap[i%200];
}

// tiled: block = (hb: 32 h-rows, kb: 500 k). Wmap tile in LDS (64KB), rnn slice
// staged per t. 8 lanes per h row, float2 LDS dots, shfl-reduce, 1 atomic.
__global__ __launch_bounds__(256,2) void k_imgemm(const float* __restrict__ rnn,
        const float* __restrict__ Wmap, float* __restrict__ im){
  __shared__ __align__(16) float Ws[32*500];
  __shared__ __align__(16) float rnS[500];
  int hb = blockIdx.x;       // 0..6
  int kb = blockIdx.y;       // 0..59
  int h0 = hb*32;
  int nh = (h0+32<=200)?32:(200-h0);
  const int kbase = kb*500;
  for (int i=TID; i<nh*125; i+=256){
    int h = i/125, q = i%125;
    *reinterpret_cast<float4*>(&Ws[h*500 + q*4]) =
      *reinterpret_cast<const float4*>(&Wmap[(h0+h)*30000 + kbase + q*4]);
  }
  int h = TID>>3, sub = TID&7;
  bool act = (h < nh);
  __syncthreads();
  for (int t=0;t<60;t++){
    if (TID<125)
      *reinterpret_cast<float4*>(&rnS[TID*4]) =
        *reinterpret_cast<const float4*>(&rnn[t*30000 + kbase + TID*4]);
    __syncthreads();
    float a = 0.f;
    if (act){
      const float2* wp = reinterpret_cast<const float2*>(&Ws[h*500]);
      const float2* rp = reinterpret_cast<const float2*>(rnS);
      for (int k2=sub;k2<250;k2+=8){
        float2 wv=wp[k2], rv=rp[k2];
        a = fmaf(wv.x,rv.x,a); a = fmaf(wv.y,rv.y,a);
      }
    }
    a += __shfl_down(a,4); a += __shfl_down(a,2); a += __shfl_down(a,1);
    if (act && sub==0) atomicAdd(&im[t*200 + h0 + h], a);
    __syncthreads();
  }
}

// ---------------- LSTM pre-gates ----------------
__global__ void k_pregates(const float* __restrict__ x, const float* __restrict__ Wih,
                           const float* __restrict__ bih, const float* __restrict__ bhh,
                           float* __restrict__ pre){
  __shared__ float xS[200];
  int t = blockIdx.x;
  if (TID<200) xS[TID] = x[t*200+TID];
  __syncthreads();
  int r = blockIdx.y*256 + TID;
  if (r>=800) return;
  float a = bih[r] + bhh[r];
  const float* wp = Wih + r*200;
  #pragma unroll 4
  for (int c=0;c<200;c++) a = fmaf(wp[c], xS[c], a);
  pre[t*800+r] = a;
}

// ---------------- LSTM recurrent: weights in 25 named int4 regs (f16) ----------------
__global__ __launch_bounds__(768,3) void k_lstm(const float* __restrict__ pre,
        const __half* __restrict__ WhhH, float* __restrict__ out){
  __shared__ __align__(16) float hsF[200];
  __shared__ float gsh[800];
  __shared__ __half wtH[32*200];
  for (int i=TID;i<6400;i+=768) wtH[i] = WhhH[768*200 + i];
  const int4* wrow = reinterpret_cast<const int4*>(WhhH + TID*200);
#define DECLW(n) int4 w##n = wrow[n];
  REP25(DECLW)
#undef DECLW
  float c_reg = 0.f;
  if (TID<200) hsF[TID]=0.f;
  int j = TID - 512;
  int trow = (j>=0) ? (j>>3) : 0;
  int tseg = (j>=0) ? (j&7)*25 : 0;
  float p = pre[TID];
  __syncthreads();
  for (int t=0;t<60;t++){
    float pn = pre[((t<59)?(t+1):t)*800 + TID];
    float a0=0.f,a1=0.f,a2=0.f,a3=0.f;
    const float4* hs4 = reinterpret_cast<const float4*>(hsF);
#define DOTW(n) { U16B u; u.i = w##n; \
    float4 hA = hs4[2*(n)], hB = hs4[2*(n)+1]; \
    float2 q0=__half22float2(u.h2[0]), q1=__half22float2(u.h2[1]); \
    float2 q2=__half22float2(u.h2[2]), q3=__half22float2(u.h2[3]); \
    a0=fmaf(q0.x,hA.x,a0); a1=fmaf(q0.y,hA.y,a1); \
    a2=fmaf(q1.x,hA.z,a2); a3=fmaf(q1.y,hA.w,a3); \
    a0=fmaf(q2.x,hB.x,a0); a1=fmaf(q2.y,hB.y,a1); \
    a2=fmaf(q3.x,hB.z,a2); a3=fmaf(q3.y,hB.w,a3); }
    REP25(DOTW)
#undef DOTW
    gsh[TID] = a0+a1+a2+a3 + p;
    if (j>=0){
      float pa = 0.f;
      const __half* wt = &wtH[trow*200 + tseg];
      const float* hp = &hsF[tseg];
      #pragma unroll
      for (int c2=0;c2<25;c2++) pa = fmaf(__half2float(wt[c2]), hp[c2], pa);
      pa += __shfl_down(pa,4); pa += __shfl_down(pa,2); pa += __shfl_down(pa,1);
      if ((j&7)==0) gsh[768+trow] = pa + pre[t*800+768+trow];
    }
    p = pn;
    __syncthreads();
    if (TID<200){
      float ii=gsh[TID], ff=gsh[200+TID], gg=gsh[400+TID], oo=gsh[600+TID];
      float c = sigf(ff)*c_reg + sigf(ii)*tanhf(gg);
      c_reg = c;
      float h = sigf(oo)*tanhf(c);
      hsF[TID]=h;
      out[t*200+TID]=h;
    }
    __syncthreads();
  }
}

// ---------------- eta chain (single block) ----------------
__global__ void k_eta(const float* __restrict__ outF, const float* __restrict__ Wmu,
                      const float* __restrict__ bmu, const float* __restrict__ Wls,
                      const float* __restrict__ bls, const float* __restrict__ eps,
                      float* __restrict__ etas, float* acc){
  __shared__ __half wS[100*254];
  __shared__ float inp[256];
  __shared__ float pt[200];
  __shared__ float muS[64], lsS[64];
  for (int i=TID;i<12500;i+=256) wS[(i/250)*254 + (i%250)] = __float2half_rn(Wmu[i]);
  for (int i=TID;i<12500;i+=256) wS[(50+i/250)*254 + (i%250)] = __float2half_rn(Wls[i]);
  if (TID<50) inp[200+TID]=0.f;
  const float LOGD = logf(0.005f);
  float kacc = 0.f;
  __syncthreads();
  for (int t=0;t<60;t++){
    if (TID<200) inp[TID] = outF[t*200+TID];
    __syncthreads();
    if (TID<200){
      int rr = TID%100, hf = TID/100;
      const __half* wp = &wS[rr*254 + hf*125];
      const float* ip = &inp[hf*125];
      float s=0.f;
      for (int c=0;c<125;c++) s = fmaf(__half2float(wp[c]), ip[c], s);
      pt[TID]=s;
    }
    __syncthreads();
    if (TID<100){
      float v = pt[TID]+pt[TID+100];
      if (TID<50) muS[TID] = v + bmu[TID];
      else lsS[TID-50] = v + bls[TID-50];
    }
    __syncthreads();
    if (TID<64){
      float term=0.f;
      if (TID<50){
        float mu=muS[TID], ls=lsS[TID], ep=inp[200+TID];
        if (t==0) term = (expf(ls)+mu*mu)*(1.0f/(1.0f+1e-6f)) - 1.f - ls;
        else { float d=mu-ep; term = (expf(ls)+d*d)*(1.0f/(0.005f+1e-6f)) - 1.f + LOGD - ls; }
        float et = mu + eps[t*50+TID]*expf(0.5f*ls);
        etas[t*50+TID]=et;
        inp[200+TID]=et;
      }
      for (int o=32;o>0;o>>=1) term += __shfl_down(term,o);
      if (TID==0) kacc += 0.5f*term;
    }
    __syncthreads();
  }
  if (TID==0) atomicAdd(acc+1, kacc);
}

// ---------------- h1 = qt_in @ W1.T + b1 (atomic k-split GEMM) ----------------
__global__ void k_h1init(float* __restrict__ h1, const float* __restrict__ b1){
  int i = blockIdx.x*256+TID; if (i<102400) h1[i] = b1[i%800];
}

__global__ void k_h1gemm(const float* __restrict__ nb, const int* __restrict__ times,
                         const float* __restrict__ etas, const float* __restrict__ W1,
                         float* __restrict__ h1){
  __shared__ __align__(16) float As[16*132];
  __shared__ __align__(16) float Ws[16*68];
  __shared__ int tS[128];
  if (TID<128) tS[TID]=times[TID];
  int rt = blockIdx.x, sp = blockIdx.y;
  int kbeg = sp*940;
  int kend = (kbeg+940<30050)?(kbeg+940):30050;
  int b0 = (TID%32)*4, r0 = (TID/32)*8;
  float acc[32];
  #pragma unroll
  for (int j=0;j<32;j++) acc[j]=0.f;
  for (int kb=kbeg; kb<kend; kb+=16){
    __syncthreads();
    for (int i=TID;i<2048;i+=256){
      int b=i/16, kk=i%16, kg=kb+kk;
      float v=0.f;
      if (kg<kend){ v = (kg<30000)? nb[b*30000+kg] : etas[tS[b]*50 + (kg-30000)]; }
      As[kk*132+b]=v;
    }
    for (int i=TID;i<1024;i+=256){
      int r=i/16, kk=i%16, kg=kb+kk, rg=rt*64+r;
      float v=0.f;
      if (kg<kend && rg<800) v = W1[rg*30050+kg];
      Ws[kk*68+r]=v;
    }
    __syncthreads();
    #pragma unroll
    for (int kk=0;kk<16;kk++){
      float4 a4 = *reinterpret_cast<const float4*>(&As[kk*132+b0]);
      float4 w4 = *reinterpret_cast<const float4*>(&Ws[kk*68+r0]);
      float4 w5 = *reinterpret_cast<const float4*>(&Ws[kk*68+r0+4]);
      float aa[4]={a4.x,a4.y,a4.z,a4.w};
      float ww[8]={w4.x,w4.y,w4.z,w4.w,w5.x,w5.y,w5.z,w5.w};
      #pragma unroll
      for (int j=0;j<4;j++)
        #pragma unroll
        for (int i2=0;i2<8;i2++) acc[j*8+i2] = fmaf(aa[j], ww[i2], acc[j*8+i2]);
    }
  }
  #pragma unroll
  for (int j=0;j<4;j++){
    int b=b0+j;
    #pragma unroll
    for (int i2=0;i2<8;i2++){
      int rg = rt*64+r0+i2;
      if (rg<800) atomicAdd(&h1[b*800+rg], acc[j*8+i2]);
    }
  }
}

// ---------------- h2 = relu(relu(h1) @ W2.T + b2), tiled 32x64 ----------------
__global__ __launch_bounds__(256) void k_h2(const float* __restrict__ h1,
        const float* __restrict__ W2, const float* __restrict__ b2,
        float* __restrict__ h2){
  __shared__ __align__(16) float As[16*33];
  __shared__ __align__(16) float Ws[16*68];
  int bt = blockIdx.x;  // 0..3  (32 docs)
  int rt = blockIdx.y;  // 0..12 (64 rows)
  int b0 = (TID%16)*2, r0 = (TID/16)*4;
  float acc[8] = {0,0,0,0,0,0,0,0};
  for (int kb=0; kb<800; kb+=16){
    __syncthreads();
    for (int i=TID;i<512;i+=256){
      int b=i>>4, k=i&15;
      As[k*33+b] = fmaxf(h1[(bt*32+b)*800 + kb + k], 0.f);
    }
    for (int i=TID;i<1024;i+=256){
      int r=i>>4, k=i&15; int rg = rt*64+r;
      Ws[k*68+r] = (rg<800) ? W2[rg*800 + kb + k] : 0.f;
    }
    __syncthreads();
    #pragma unroll
    for (int k=0;k<16;k++){
      float a0=As[k*33+b0], a1=As[k*33+b0+1];
      float4 w4 = *reinterpret_cast<const float4*>(&Ws[k*68+r0]);
      acc[0]=fmaf(a0,w4.x,acc[0]); acc[1]=fmaf(a0,w4.y,acc[1]);
      acc[2]=fmaf(a0,w4.z,acc[2]); acc[3]=fmaf(a0,w4.w,acc[3]);
      acc[4]=fmaf(a1,w4.x,acc[4]); acc[5]=fmaf(a1,w4.y,acc[5]);
      acc[6]=fmaf(a1,w4.z,acc[6]); acc[7]=fmaf(a1,w4.w,acc[7]);
    }
  }
  #pragma unroll
  for (int jj=0;jj<2;jj++){
    int b = bt*32 + b0 + jj;
    #pragma unroll
    for (int i2=0;i2<4;i2++){
      int rg = rt*64 + r0 + i2;
      if (rg<800) h2[b*800+rg] = fmaxf(acc[jj*4+i2] + b2[rg], 0.f);
    }
  }
}

// ---------------- mu_th / ls_th ----------------
__global__ void k_muls(const float* __restrict__ h2, const float* __restrict__ Wmu,
                       const float* __restrict__ bmu, const float* __restrict__ Wls,
                       const float* __restrict__ bls, float* __restrict__ muth,
                       float* __restrict__ lsth){
  __shared__ float hS[800];
  int b = blockIdx.x;
  for (int i=TID;i<800;i+=128) hS[i] = h2[b*800+i];
  __syncthreads();
  if (TID<50){
    float a = bmu[TID];
    const float* wp = Wmu + TID*800;
    #pragma unroll 4
    for (int c=0;c<800;c++) a = fmaf(wp[c], hS[c], a);
    muth[b*50+TID]=a;
  } else if (TID>=64 && TID<114){
    int r = TID-64;
    float a = bls[r];
    const float* wp = Wls + r*800;
    #pragma unroll 4
    for (int c=0;c<800;c++) a = fmaf(wp[c], hS[c], a);
    lsth[b*50+r]=a;
  }
}

// ---------------- theta + kl_theta ----------------
__global__ void k_theta(const float* __restrict__ muth, const float* __restrict__ lsth,
                        const float* __restrict__ etas, const int* __restrict__ times,
                        const float* __restrict__ epsth, float* __restrict__ theta,
                        float* acc){
  int b = blockIdx.x, k = TID;
  bool a = k<50;
  int tb = times[b];
  float mu=0.f, ls=0.f, etd=0.f, z=-INFINITY;
  if (a){
    mu = muth[b*50+k]; ls = lsth[b*50+k]; etd = etas[tb*50+k];
    z = mu + epsth[b*50+k]*expf(0.5f*ls);
  }
  float m=z;
  for (int o=32;o>0;o>>=1) m = fmaxf(m, __shfl_xor(m,o));
  float e = a ? expf(z-m) : 0.f;
  float s = e;
  for (int o=32;o>0;o>>=1) s += __shfl_xor(s,o);
  if (a) theta[b*50+k] = e/s;
  float term = a ? ((expf(ls)+(mu-etd)*(mu-etd))*(1.0f/(1.0f+1e-6f)) - 1.f - ls) : 0.f;
  for (int o=32;o>0;o>>=1) term += __shfl_xor(term,o);
  if (TID==0) atomicAdd(acc+2, 0.5f*term);
}

// ---------------- MFMA beta pass 1 ----------------
__global__ __launch_bounds__(256,2) void k_mf1(const unsigned short* __restrict__ rho_f,
        const unsigned short* __restrict__ alpha_f,
        float* __restrict__ Mp, float* __restrict__ Sp){
  int vb = blockIdx.x, tg = blockIdx.y;
  int wid = TID>>6, lane = TID&63;
  int r32 = vb*4 + wid;
  const int4* ap = ((const int4*)rho_f) + (r32*19)*64 + lane;
  int4 a[19];
  #pragma unroll
  for (int ks=0;ks<19;ks++) a[ks] = ap[ks*64];
  __shared__ float redM[4][64];
  __shared__ float redS[4][64];
  int rowbase = vb*128 + wid*32 + ((lane>>5)<<2);
  for (int t = tg*15; t < tg*15+15; t++){
    v16f acc0, acc1;
    #pragma unroll
    for (int i=0;i<16;i++){ acc0[i]=0.f; acc1[i]=0.f; }
    const int4* bp = ((const int4*)alpha_f) + (t*38)*64 + lane;
    #pragma unroll
    for (int ks=0;ks<19;ks++){
      I4BF av, b0, b1;
      av.i = a[ks];
      b0.i = bp[ks*64];
      b1.i = bp[(19+ks)*64];
      acc0 = __builtin_amdgcn_mfma_f32_32x32x16_bf16(av.s, b0.s, acc0, 0,0,0);
      acc1 = __builtin_amdgcn_mfma_f32_32x32x16_bf16(av.s, b1.s, acc1, 0,0,0);
    }
    float m0=-INFINITY, m1=-INFINITY;
    #pragma unroll
    for (int r=0;r<16;r++){
      int v = rowbase + (r&3) + ((r>>2)<<3);
      if (v < 30000){ m0 = fmaxf(m0, acc0[r]); m1 = fmaxf(m1, acc1[r]); }
    }
    m0 = fmaxf(m0, __shfl_xor(m0, 32));
    m1 = fmaxf(m1, __shfl_xor(m1, 32));
    float s0=0.f, s1=0.f;
    #pragma unroll
    for (int r=0;r<16;r++){
      int v = rowbase + (r&3) + ((r>>2)<<3);
      if (v < 30000){ s0 += expf(acc0[r]-m0); s1 += expf(acc1[r]-m1); }
    }
    s0 += __shfl_xor(s0, 32);
    s1 += __shfl_xor(s1, 32);
    if (lane < 32){
      redM[wid][lane] = m0; redM[wid][lane+32] = m1;
      redS[wid][lane] = s0; redS[wid][lane+32] = s1;
    }
    __syncthreads();
    if (TID < 50){
      float M = redM[0][TID];
      #pragma unroll
      for (int w2=1; w2<4; w2++) M = fmaxf(M, redM[w2][TID]);
      float S = 0.f;
      #pragma unroll
      for (int w2=0; w2<4; w2++){
        float mw = redM[w2][TID];
        if (mw > -INFINITY) S += redS[w2][TID] * expf(mw - M);
      }
      Mp[(t*50+TID)*NVB + vb] = M;
      Sp[(t*50+TID)*NVB + vb] = S;
    }
    __syncthreads();
  }
}

// ---------------- reduce partials -> M, 1/S ----------------
__global__ void k_msred(const float* __restrict__ Mp, const float* __restrict__ Sp,
                        float* __restrict__ Mg, float* __restrict__ iSg){
  __shared__ float red[256];
  int row = blockIdx.x;
  float m = (TID<NVB) ? Mp[row*NVB+TID] : -INFINITY;
  red[TID]=m; __syncthreads();
  for (int s=128;s>0;s>>=1){ if (TID<s) red[TID]=fmaxf(red[TID],red[TID+s]); __syncthreads(); }
  float M = red[0]; __syncthreads();
  float sv = (TID<NVB) ? Sp[row*NVB+TID]*expf(m-M) : 0.f;
  red[TID]=sv; __syncthreads();
  for (int s=128;s>0;s>>=1){ if (TID<s) red[TID]+=red[TID+s]; __syncthreads(); }
  if (TID==0){ Mg[row]=M; iSg[row]=1.f/red[0]; }
}

// ---------------- MFMA beta pass 2: recompute, normalize, fuse nll ----------------
__global__ __launch_bounds__(256,2) void k_mf2(const unsigned short* __restrict__ rho_f,
        const unsigned short* __restrict__ alpha_f,
        const float* __restrict__ Mg, const float* __restrict__ iSg,
        const float* __restrict__ theta, const int* __restrict__ times,
        const float* __restrict__ bows, float* acc){
  __shared__ float thS[128*52];
  __shared__ float tileS[4][32*66];
  __shared__ int tS[128];
  __shared__ int cntS[64];
  int vb = blockIdx.x, tg = blockIdx.y;
  int wid = TID>>6, lane = TID&63;
  if (TID < 64) cntS[TID] = 0;
  __syncthreads();
  if (TID < 128){ int tv = times[TID]; tS[TID] = tv; atomicAdd(&cntS[tv], 1); }
  for (int i=TID; i<6400; i+=256){ int b=i/50, c=i%50; thS[b*52+c] = theta[i]; }
  int r32 = vb*4 + wid;
  const int4* ap = ((const int4*)rho_f) + (r32*19)*64 + lane;
  int4 a[19];
  #pragma unroll
  for (int ks=0;ks<19;ks++) a[ks] = ap[ks*64];
  __syncthreads();
  float local = 0.f;
  int rb32 = ((lane>>5)<<2);
  int c0 = lane&31, c1 = 32 + (lane&31);
  for (int t = tg*15; t < tg*15+15; t++){
    if (cntS[t] == 0) continue;
    v16f acc0, acc1;
    #pragma unroll
    for (int i=0;i<16;i++){ acc0[i]=0.f; acc1[i]=0.f; }
    const int4* bp = ((const int4*)alpha_f) + (t*38)*64 + lane;
    #pragma unroll
    for (int ks=0;ks<19;ks++){
      I4BF av, b0, b1;
      av.i = a[ks];
      b0.i = bp[ks*64];
      b1.i = bp[(19+ks)*64];
      acc0 = __builtin_amdgcn_mfma_f32_32x32x16_bf16(av.s, b0.s, acc0, 0,0,0);
      acc1 = __builtin_amdgcn_mfma_f32_32x32x16_bf16(av.s, b1.s, acc1, 0,0,0);
    }
    float M0 = Mg[t*50+c0], i0 = iSg[t*50+c0];
    float M1 = 0.f, i1 = 0.f;
    if (c1 < 50){ M1 = Mg[t*50+c1]; i1 = iSg[t*50+c1]; }
    float* tl = &tileS[wid][0];
    #pragma unroll
    for (int r=0;r<16;r++){
      int row = rb32 + (r&3) + ((r>>2)<<3);
      tl[row*66 + c0] = expf(acc0[r]-M0)*i0;
      if (c1 < 50) tl[row*66 + c1] = expf(acc1[r]-M1)*i1;
    }
    __syncthreads();
    for (int b=0;b<128;b++){
      if (tS[b] != t) continue;
      int row = lane&31;
      int v = vb*128 + wid*32 + row;
      const float* th = &thS[b*52 + (lane>>5)*25];
      const float* tp = &tl[row*66 + (lane>>5)*25];
      float mix = 0.f;
      #pragma unroll 5
      for (int c=0;c<25;c++) mix = fmaf(th[c], tp[c], mix);
      mix += __shfl_xor(mix, 32);
      if (lane < 32 && v < 30000)
        local -= logf(mix + 1e-6f) * bows[b*30000 + v];
    }
    __syncthreads();
  }
  for (int o=1;o<64;o<<=1) local += __shfl_xor(local, o);
  if (lane==0) atomicAdd(acc+3, local);
}

// ---------------- finalize ----------------
__global__ void k_final(const float* __restrict__ acc, const int* __restrict__ nd,
                        float* __restrict__ out){
  float coeff = (float)(*nd) / 128.0f;
  float nll = acc[3]*coeff;
  float klth = acc[2]*coeff;
  out[0] = nll + acc[0] + acc[1] + klth;
  out[1] = nll;
  out[2] = acc[0];
  out[3] = acc[1];
  out[4] = klth;
}

extern "C" void kernel_launch(void* const* d_in, const int* in_sizes, int n_in,
                              void* d_out, int out_size, void* d_ws, size_t ws_size,
                              hipStream_t stream) {
  (void)in_sizes; (void)n_in; (void)out_size; (void)ws_size;
  const float* bows  = (const float*)d_in[0];
  const float* nb    = (const float*)d_in[1];
  const int*   times = (const int*)d_in[2];
  const float* rnn   = (const float*)d_in[3];
  const int*   ndocs = (const int*)d_in[4];
  const float* eps_a = (const float*)d_in[5];
  const float* eps_e = (const float*)d_in[6];
  const float* eps_t = (const float*)d_in[7];
  const float* rho   = (const float*)d_in[8];
  const float* mqa   = (const float*)d_in[9];
  const float* lqa   = (const float*)d_in[10];
  const float* W1    = (const float*)d_in[11];
  const float* b1    = (const float*)d_in[12];
  const float* W2    = (const float*)d_in[13];
  const float* b2    = (const float*)d_in[14];
  const float* Wmu_t = (const float*)d_in[15];
  const float* bmu_t = (const float*)d_in[16];
  const float* Wls_t = (const float*)d_in[17];
  const float* bls_t = (const float*)d_in[18];
  const float* Wmap  = (const float*)d_in[19];
  const float* bmap  = (const float*)d_in[20];
  const float* Wih   = (const float*)d_in[21];
  const float* Whh   = (const float*)d_in[22];
  const float* bih   = (const float*)d_in[23];
  const float* bhh   = (const float*)d_in[24];
  const float* Wmu_e = (const float*)d_in[25];
  const float* bmu_e = (const float*)d_in[26];
  const float* Wls_e = (const float*)d_in[27];
  const float* bls_e = (const float*)d_in[28];
  float* out = (float*)d_out;

  float* w      = (float*)d_ws;
  float* acc    = w;                        // 8
  unsigned short* rho_f   = (unsigned short*)(w + 8);           // 4,569,600 f
  unsigned short* alpha_f = (unsigned short*)(w + 8 + 4569600); // 583,680 f
  float* alphas = w + 8 + 4569600 + 583680; // 900000
  float* im     = alphas + 900000;          // 12000
  float* outA   = im + 12000;               // 12000
  float* outB   = outA + 12000;             // 12000
  float* pre    = outB + 12000;             // 48000
  float* etas   = pre + 48000;              // 3000
  float* h1     = etas + 3000;              // 102400
  float* h2     = h1 + 102400;              // 102400
  float* muth   = h2 + 102400;              // 6400
  float* lsth   = muth + 6400;              // 6400
  float* theta  = lsth + 6400;              // 6400
  float* Mp     = theta + 6400;             // 705000
  float* Sp     = Mp + 705000;              // 705000
  float* Mg     = Sp + 705000;              // 3000
  float* iSg    = Mg + 3000;                // 3000
  __half* whhH  = (__half*)(iSg + 3000);    // 480000 halves

  k_zero<<<1,64,0,stream>>>(acc);
  k_alphas<<<3516,256,0,stream>>>(mqa, lqa, eps_a, alphas);
  k_klalpha<<<3516,256,0,stream>>>(mqa, lqa, alphas, acc);
  k_prep_rho<<<4465,256,0,stream>>>(rho, rho_f);
  k_prep_alpha<<<570,256,0,stream>>>(alphas, alpha_f);
  k_prep_whh<<<1875,256,0,stream>>>(Whh, whhH);
  k_iminit<<<47,256,0,stream>>>(im, bmap);
  k_imgemm<<<dim3(7,60),256,0,stream>>>(rnn, Wmap, im);

  const float* x = im;
  float* bufs[2] = {outA, outB};
  for (int l=0;l<3;l++){
    float* o = bufs[l%2];
    k_pregates<<<dim3(60,4),256,0,stream>>>(x, Wih + l*160000, bih + l*800, bhh + l*800, pre);
    k_lstm<<<1,768,0,stream>>>(pre, whhH + l*160000, o);
    x = o;
  }
  const float* lstm_out = x;

  k_eta<<<1,256,0,stream>>>(lstm_out, Wmu_e, bmu_e, Wls_e, bls_e, eps_e, etas, acc);
  k_h1init<<<400,256,0,stream>>>(h1, b1);
  k_h1gemm<<<dim3(13,32),256,0,stream>>>(nb, times, etas, W1, h1);
  k_h2<<<dim3(4,13),256,0,stream>>>(h1, W2, b2, h2);
  k_muls<<<128,128,0,stream>>>(h2, Wmu_t, bmu_t, Wls_t, bls_t, muth, lsth);
  k_theta<<<128,64,0,stream>>>(muth, lsth, etas, times, eps_t, theta, acc);
  k_mf1<<<dim3(NVB,4),256,0,stream>>>(rho_f, alpha_f, Mp, Sp);
  k_msred<<<3000,256,0,stream>>>(Mp, Sp, Mg, iSg);
  k_mf2<<<dim3(NVB,4),256,0,stream>>>(rho_f, alpha_f, Mg, iSg, theta, times, bows, acc);
  k_final<<<1,1,0,stream>>>(acc, ndocs, out);
}